// Round 3
// baseline (6266.038 us; speedup 1.0000x reference)
//
#include <hip/hip_runtime.h>
#include <math.h>

#define BB 256
#define NN 1000
#define DD 128
#define HH 8
#define NP 1024
#define CHROWS 128
#define CLIPV 10.0f
#define SC_QK 0.25f                       // 1/sqrt(16)
#define SC_LG 0.08838834764831845f        // 1/sqrt(128)
#define NEGINF (-INFINITY)
#define LP_FLOOR (-3.0e38f)               // finite stand-in for -inf in output

typedef float  fx4 __attribute__((ext_vector_type(4)));
typedef unsigned short usx4 __attribute__((ext_vector_type(4)));

__device__ __forceinline__ float dot4(float4 a, float4 b) {
    return fmaf(a.x, b.x, fmaf(a.y, b.y, fmaf(a.z, b.z, a.w * b.w)));
}
__device__ __forceinline__ float4 fma4(float p, float4 e, float4 a) {
    a.x = fmaf(p, e.x, a.x); a.y = fmaf(p, e.y, a.y);
    a.z = fmaf(p, e.z, a.z); a.w = fmaf(p, e.w, a.w);
    return a;
}
__device__ __forceinline__ void bf2f(unsigned int u, float& a, float& b) {
    union { unsigned int i; float f; } lo, hi;
    lo.i = u << 16; hi.i = u & 0xffff0000u;
    a = lo.f; b = hi.f;
}
__device__ __forceinline__ unsigned short f2bf_rne(float x) {
    union { float f; unsigned int u; } v; v.f = x;
    unsigned int r = v.u + 0x7FFFu + ((v.u >> 16) & 1u);
    return (unsigned short)(r >> 16);
}
// async global->LDS, 16B per lane; LDS dest is wave-uniform base + lane*16
__device__ __forceinline__ void gl_lds16(const unsigned short* g, unsigned short* l) {
    __builtin_amdgcn_global_load_lds(
        (__attribute__((address_space(1))) void*)(g),
        (__attribute__((address_space(3))) void*)(l), 16, 0, 0);
}
// counted waits: N = number of newest loads allowed to stay in flight.
__device__ __forceinline__ void wait_vm2() {
    asm volatile("s_waitcnt vmcnt(2)" ::: "memory");
}
__device__ __forceinline__ void wait_vm0() {
    asm volatile("s_waitcnt vmcnt(0)" ::: "memory");
}
// raw barrier (no vmcnt drain) pinned against scheduler motion
__device__ __forceinline__ void block_bar() {
    __builtin_amdgcn_sched_barrier(0);
    __builtin_amdgcn_s_barrier();
    __builtin_amdgcn_sched_barrier(0);
}

// ---------------- fp32 emb -> bf16 scratch copy, padded to 1024 rows ----------------
__global__ __launch_bounds__(256) void conv_bf16_pad(const float* __restrict__ emb,
                                                     unsigned short* __restrict__ ebf) {
    const int idx = blockIdx.x * 256 + threadIdx.x;     // one 8-bf16 unit (16B out)
    const int b   = idx >> 14;                          // / (1024*16)
    const int row = (idx >> 4) & 1023;
    const int k8  = idx & 15;
    uint4 o = make_uint4(0u, 0u, 0u, 0u);               // pad rows -> zeros
    if (row < NN) {
        const float* p = emb + ((size_t)b * NN + row) * DD + k8 * 8;
        fx4 f0 = __builtin_nontemporal_load((const fx4*)p);
        fx4 f1 = __builtin_nontemporal_load((const fx4*)(p + 4));
        o.x = ((unsigned)f2bf_rne(f0.y) << 16) | f2bf_rne(f0.x);
        o.y = ((unsigned)f2bf_rne(f0.w) << 16) | f2bf_rne(f0.z);
        o.z = ((unsigned)f2bf_rne(f1.y) << 16) | f2bf_rne(f1.x);
        o.w = ((unsigned)f2bf_rne(f1.w) << 16) | f2bf_rne(f1.z);
    }
    *(uint4*)(ebf + (size_t)idx * 8) = o;
}

// ---------------- main decoder (bf16 sweeps, LDS-staged, counted-vmcnt pipeline) ----------------
__global__ __launch_bounds__(1024, 4) void ar_decoder_bf16(
    const float* __restrict__ emb,            // [B][N][D] fp32 (small reads only)
    const unsigned short* __restrict__ embbf, // [B][1024][D] bf16 padded (sweeps)
    const float* __restrict__ Wn,    // [D][3D]  (gk | gv | lk columns)
    const float* __restrict__ Wf,    // [D][D]
    const float* __restrict__ Wc,    // [2D][D]
    const float* __restrict__ Wo,    // [D][D]
    const int*  __restrict__ nsp,    // num_steps
    float* __restrict__ out)         // [B][S][N] log_p then [B][S] actions (as float)
{
    const int b = blockIdx.x;
    const int t = threadIdx.x;
    const int S = nsp[0];
    const float* E  = emb + (size_t)b * (NN * DD);
    const unsigned short* Ebf = embbf + (size_t)b * (1024 * DD);
    const int wv = t >> 6, ln = t & 63;

    __shared__ __align__(16) unsigned short ebuf[3][CHROWS * DD];  // 3 x 32KB staging
    __shared__ __align__(16) float pS[8192];       // scores/p [n][8]; also wsum scratch
    __shared__ __align__(16) float qkT[HH * 132];  // qk [h][132] padded
    __shared__ __align__(16) float wsumL[HH * DD];
    __shared__ __align__(16) float maskF[NP];      // 0 = live, -inf = visited/pad
    __shared__ __align__(16) float zS[NP];         // clipped+masked logits
    __shared__ __align__(16) float ceL[DD], qL[DD], gL[DD], fL[DD], uL[DD];
    __shared__ __align__(16) float fcL[DD], muL[DD], e0L[DD];
    __shared__ __align__(16) float wredM[128], wredS[128];
    __shared__ float mL[HH], lL[HH];
    __shared__ float redA[16], redV[16];
    __shared__ int   redI[16];
    __shared__ float maxvL, logSL;
    __shared__ int   curL, amaxL;

    // stage one 128-row chunk (32KB) of Ebf into ebuf[bi]; all 16 waves, 2KB each
#define STAGE_CHUNK(cidx, bi) do {                                             \
        const unsigned short* _s = Ebf + (size_t)(cidx) * (CHROWS * DD);       \
        unsigned short* _d = &ebuf[bi][0];                                     \
        gl_lds16(_s + wv * 512 + ln * 8,        _d + wv * 512);                \
        gl_lds16(_s + (16 + wv) * 512 + ln * 8, _d + (16 + wv) * 512);         \
    } while (0)

    // ---------------- prologue ----------------
    {   // mean over nodes (8 strips of 125)
        const int d = t & 127, strip = t >> 7;
        float acc = 0.f;
        const int n0 = strip * 125;
        for (int k = 0; k < 125; ++k) acc += E[(n0 + k) * DD + d];
        pS[strip * 128 + d] = acc;
    }
    if (t < DD) e0L[t] = E[t];
    __syncthreads();
    if (t < DD) {
        float ssum = 0.f;
        for (int k = 0; k < 8; ++k) ssum += pS[k * 128 + t];
        muL[t] = ssum * (1.0f / (float)NN);
    }
    __syncthreads();
    if (t < DD) {
        float fc = 0.f;
        for (int i = 0; i < DD; ++i)
            fc += muL[i] * Wf[i * DD + t] + e0L[i] * Wc[i * DD + t];
        fcL[t] = fc;
    }
    maskF[t] = (t == 0 || t >= NN) ? NEGINF : 0.f;
    if (t == 0) curL = 0;
    __syncthreads();

    const size_t out_lp_base = (size_t)b * S * NN;
    const size_t act_base    = (size_t)BB * S * NN + (size_t)b * S;

    for (int s = 0; s < S; ++s) {
        // (0) current node embedding (fp32, exact)
        if (t < DD) ceL[t] = E[curL * DD + t];
        __syncthreads();
        // (1) q = fc + cur_emb @ Wc_bottom  (8-way k-split per output)
        {
            const int d = t >> 3, p = t & 7;
            const int i0 = p * 16;
            float q = 0.f;
            #pragma unroll
            for (int i = 0; i < 16; ++i)
                q += ceL[i0 + i] * Wc[(DD + i0 + i) * DD + d];
            q += __shfl_xor(q, 1);
            q += __shfl_xor(q, 2);
            q += __shfl_xor(q, 4);
            if (p == 0) qL[d] = q + fcL[d];
        }
        __syncthreads();
        // (2) qk[h][d] = 0.25 * sum_k Wk[d][h*16+k] * q[h*16+k]
        {
            const int h = t >> 7, d = t & 127;
            float v = 0.f;
            for (int k = 0; k < 16; ++k)
                v += Wn[d * 384 + h * 16 + k] * qL[h * 16 + k];
            qkT[h * 132 + d] = v * SC_QK;
        }
        __syncthreads();
        // (3) scores sweep, 3-buf depth-2 pipeline; fused masked-max tracking
        {
            const int dq = t & 3, h = (t >> 2) & 7, o = t >> 5;   // o in 0..31
            float4 qk4[8];                 // chunks c = dq+4m, elems [c*8, c*8+8)
            #pragma unroll
            for (int m = 0; m < 4; ++m) {
                const float* qp = &qkT[h * 132 + (dq + 4 * m) * 8];
                qk4[2 * m]     = *(const float4*)(qp);
                qk4[2 * m + 1] = *(const float4*)(qp + 4);
            }
            STAGE_CHUNK(0, 0);
            STAGE_CHUNK(1, 1);
            wait_vm2();                    // chunk 0 landed; chunk 1 in flight
            block_bar();
            float mloc = NEGINF;
            int rb = 0, wb = 2;
            for (int c = 0; c < 8; ++c) {
                if (c < 6) { STAGE_CHUNK(c + 2, wb); wb = (wb == 2) ? 0 : wb + 1; }
                const unsigned short* Eb = &ebuf[rb][0];
                float acc[4];
                #pragma unroll
                for (int j = 0; j < 4; ++j) acc[j] = 0.f;
                #pragma unroll
                for (int j = 0; j < 4; ++j) {
                    const int r = o * 4 + j;
                    const uint4* rp = (const uint4*)(Eb + r * DD);
                    #pragma unroll
                    for (int m = 0; m < 4; ++m) {
                        uint4 u = rp[dq + 4 * m];
                        float e0,e1,e2,e3,e4,e5,e6,e7;
                        bf2f(u.x, e0, e1); bf2f(u.y, e2, e3);
                        bf2f(u.z, e4, e5); bf2f(u.w, e6, e7);
                        const float4 qa = qk4[2 * m], qb = qk4[2 * m + 1];
                        acc[j] = fmaf(e0, qa.x, fmaf(e1, qa.y, fmaf(e2, qa.z, fmaf(e3, qa.w, acc[j]))));
                        acc[j] = fmaf(e4, qb.x, fmaf(e5, qb.y, fmaf(e6, qb.z, fmaf(e7, qb.w, acc[j]))));
                    }
                }
                #pragma unroll
                for (int j = 0; j < 4; ++j) {
                    acc[j] += __shfl_xor(acc[j], 1);
                    acc[j] += __shfl_xor(acc[j], 2);
                }
                const int nb = c * 128 + o * 4;
                pS[(nb + dq) * 8 + h] = acc[dq];
                #pragma unroll
                for (int j = 0; j < 4; ++j)
                    mloc = fmaxf(mloc, acc[j] + maskF[nb + j]);   // pad rows -> -inf
                if (c < 6)      { wait_vm2(); block_bar(); }
                else if (c < 7) { wait_vm0(); block_bar(); }
                rb = (rb == 2) ? 0 : rb + 1;
            }
            // reduce over lanes sharing h (bits 0,1,5)
            mloc = fmaxf(mloc, __shfl_xor(mloc, 1));
            mloc = fmaxf(mloc, __shfl_xor(mloc, 2));
            mloc = fmaxf(mloc, __shfl_xor(mloc, 32));
            if ((t & 35) == 0) wredM[wv * 8 + h] = mloc;
        }
        __syncthreads();
        if (t < HH) {
            float m = wredM[t];
            for (int w = 1; w < 16; ++w) m = fmaxf(m, wredM[w * 8 + t]);
            mL[t] = m;
        }
        __syncthreads();
        // (4) p = exp(s + mask - m) in place + fused per-h partial sums
        {
            float4* pS4 = (float4*)pS;
            float4 a = pS4[t * 2], c = pS4[t * 2 + 1];
            const float mf = maskF[t];
            a.x = expf(a.x + mf - mL[0]); a.y = expf(a.y + mf - mL[1]);
            a.z = expf(a.z + mf - mL[2]); a.w = expf(a.w + mf - mL[3]);
            c.x = expf(c.x + mf - mL[4]); c.y = expf(c.y + mf - mL[5]);
            c.z = expf(c.z + mf - mL[6]); c.w = expf(c.w + mf - mL[7]);
            pS4[t * 2] = a; pS4[t * 2 + 1] = c;
            #pragma unroll
            for (int off = 1; off < 64; off <<= 1) {
                a.x += __shfl_xor(a.x, off); a.y += __shfl_xor(a.y, off);
                a.z += __shfl_xor(a.z, off); a.w += __shfl_xor(a.w, off);
                c.x += __shfl_xor(c.x, off); c.y += __shfl_xor(c.y, off);
                c.z += __shfl_xor(c.z, off); c.w += __shfl_xor(c.w, off);
            }
            if (ln == 0) {
                ((float4*)wredS)[wv * 2] = a;
                ((float4*)wredS)[wv * 2 + 1] = c;
            }
        }
        __syncthreads();
        if (t < HH) {
            float ssum = 0.f;
            for (int w = 0; w < 16; ++w) ssum += wredS[w * 8 + t];
            lL[t] = ssum;
        }
        // (5) wsum sweep: wsum[h][:] = sum_n p[h][n] * e[n][:]  (pipelined)
        {
            const int d8 = t & 15, g2 = (t >> 4) & 3, gh = wv & 7, hp = t >> 9;
            float acc[4][8];
            #pragma unroll
            for (int hh = 0; hh < 4; ++hh)
                #pragma unroll
                for (int i = 0; i < 8; ++i) acc[hh][i] = 0.f;
            STAGE_CHUNK(0, 0);
            STAGE_CHUNK(1, 1);
            wait_vm2();
            block_bar();
            const float4* pS4 = (const float4*)pS;
            int rb = 0, wb = 2;
            for (int c = 0; c < 8; ++c) {
                if (c < 6) { STAGE_CHUNK(c + 2, wb); wb = (wb == 2) ? 0 : wb + 1; }
                const unsigned short* Eb = &ebuf[rb][0];
                #pragma unroll
                for (int k2 = 0; k2 < 4; ++k2) {
                    const int r = k2 * 32 + gh * 4 + g2;
                    const int n = c * 128 + r;
                    uint4 u = *(const uint4*)(Eb + r * DD + d8 * 8);
                    float e[8];
                    bf2f(u.x, e[0], e[1]); bf2f(u.y, e[2], e[3]);
                    bf2f(u.z, e[4], e[5]); bf2f(u.w, e[6], e[7]);
                    const float4 p4 = pS4[n * 2 + hp];
                    #pragma unroll
                    for (int i = 0; i < 8; ++i) {
                        acc[0][i] = fmaf(p4.x, e[i], acc[0][i]);
                        acc[1][i] = fmaf(p4.y, e[i], acc[1][i]);
                        acc[2][i] = fmaf(p4.z, e[i], acc[2][i]);
                        acc[3][i] = fmaf(p4.w, e[i], acc[3][i]);
                    }
                }
                if (c < 6)      { wait_vm2(); block_bar(); }
                else if (c < 7) { wait_vm0(); block_bar(); }
                rb = (rb == 2) ? 0 : rb + 1;
            }
            __syncthreads();   // all waves done reading pS; reuse as scratch
            // reduce over g2 (lane bits 4,5)
            #pragma unroll
            for (int hh = 0; hh < 4; ++hh)
                #pragma unroll
                for (int i = 0; i < 8; ++i) {
                    acc[hh][i] += __shfl_xor(acc[hh][i], 16);
                    acc[hh][i] += __shfl_xor(acc[hh][i], 32);
                }
            if (ln < 16) {   // ln == d8, g2 == 0
                #pragma unroll
                for (int hh = 0; hh < 4; ++hh) {
                    float4* dst = (float4*)&pS[gh * 1024 + (hp * 4 + hh) * 128 + d8 * 8];
                    dst[0] = make_float4(acc[hh][0], acc[hh][1], acc[hh][2], acc[hh][3]);
                    dst[1] = make_float4(acc[hh][4], acc[hh][5], acc[hh][6], acc[hh][7]);
                }
            }
            __syncthreads();
            {
                const int h = t >> 7, d = t & 127;
                float ssum = 0.f;
                #pragma unroll
                for (int g = 0; g < 8; ++g) ssum += pS[g * 1024 + h * 128 + d];
                wsumL[h * DD + d] = ssum;
            }
            __syncthreads();
        }
        // (6) g[c] = (wsum[h]·Wv[:,c]) / l[h]   (8-way d-split)
        {
            const int c = t >> 3, p = t & 7, h = c >> 4;
            const int d0 = p * 16;
            float g = 0.f;
            #pragma unroll
            for (int i = 0; i < 16; ++i)
                g += wsumL[h * DD + d0 + i] * Wn[(d0 + i) * 384 + DD + c];
            g += __shfl_xor(g, 1);
            g += __shfl_xor(g, 2);
            g += __shfl_xor(g, 4);
            if (p == 0) gL[c] = g / lL[h];
        }
        __syncthreads();
        // (7) f = g @ W_out   (8-way i-split)
        {
            const int d = t >> 3, p = t & 7;
            const int i0 = p * 16;
            float f = 0.f;
            #pragma unroll
            for (int i = 0; i < 16; ++i)
                f += gL[i0 + i] * Wo[(i0 + i) * DD + d];
            f += __shfl_xor(f, 1);
            f += __shfl_xor(f, 2);
            f += __shfl_xor(f, 4);
            if (p == 0) fL[d] = f;
        }
        __syncthreads();
        // (8) u[d] = sc * sum_k Wl[d][k] * f[k]   (8-way k-split)
        {
            const int d = t >> 3, p = t & 7;
            const int k0 = p * 16;
            float u = 0.f;
            #pragma unroll
            for (int k = 0; k < 16; ++k)
                u += Wn[d * 384 + 256 + k0 + k] * fL[k0 + k];
            u += __shfl_xor(u, 1);
            u += __shfl_xor(u, 2);
            u += __shfl_xor(u, 4);
            if (p == 0) uL[d] = u * SC_LG;
        }
        __syncthreads();
        // (9) logits sweep (pipelined, 8 lanes/row) -> zS (clipped + masked)
        {
            const int q8 = t & 7, rr = t >> 3;   // rr in 0..127 per chunk
            const float4* uL4 = (const float4*)uL;
            const float4 ua0 = uL4[q8 * 2],       ub0 = uL4[q8 * 2 + 1];
            const float4 ua1 = uL4[(q8 + 8) * 2], ub1 = uL4[(q8 + 8) * 2 + 1];
            STAGE_CHUNK(0, 0);
            STAGE_CHUNK(1, 1);
            wait_vm2();
            block_bar();
            int rb = 0, wb = 2;
            for (int c = 0; c < 8; ++c) {
                if (c < 6) { STAGE_CHUNK(c + 2, wb); wb = (wb == 2) ? 0 : wb + 1; }
                const unsigned short* Eb = &ebuf[rb][0];
                const int n = c * 128 + rr;
                uint4 u0 = *(const uint4*)(Eb + rr * DD + q8 * 8);
                uint4 u1 = *(const uint4*)(Eb + rr * DD + (q8 + 8) * 8);
                float e0,e1,e2,e3,e4,e5,e6,e7;
                bf2f(u0.x, e0, e1); bf2f(u0.y, e2, e3);
                bf2f(u0.z, e4, e5); bf2f(u0.w, e6, e7);
                float lg;
                lg = fmaf(e0, ua0.x, fmaf(e1, ua0.y, fmaf(e2, ua0.z, e3 * ua0.w)));
                lg = fmaf(e4, ub0.x, fmaf(e5, ub0.y, fmaf(e6, ub0.z, fmaf(e7, ub0.w, lg))));
                bf2f(u1.x, e0, e1); bf2f(u1.y, e2, e3);
                bf2f(u1.z, e4, e5); bf2f(u1.w, e6, e7);
                lg = fmaf(e0, ua1.x, fmaf(e1, ua1.y, fmaf(e2, ua1.z, fmaf(e3, ua1.w, lg))));
                lg = fmaf(e4, ub1.x, fmaf(e5, ub1.y, fmaf(e6, ub1.z, fmaf(e7, ub1.w, lg))));
                lg += __shfl_xor(lg, 1);
                lg += __shfl_xor(lg, 2);
                lg += __shfl_xor(lg, 4);
                if (q8 == 0)
                    zS[n] = (n < NN) ? (CLIPV * tanhf(lg) + maskF[n]) : NEGINF;
                if (c < 6)      { wait_vm2(); block_bar(); }
                else if (c < 7) { wait_vm0(); block_bar(); }
                rb = (rb == 2) ? 0 : rb + 1;
            }
        }
        __syncthreads();
        // (10) log-softmax + argmax from zS, output, state update
        {
            const float z = zS[t];
            float v = z; int idx = t;
            #pragma unroll
            for (int off = 1; off < 64; off <<= 1) {
                float v2 = __shfl_xor(v, off);
                int   i2 = __shfl_xor(idx, off);
                if (v2 > v || (v2 == v && i2 < idx)) { v = v2; idx = i2; }
            }
            if (ln == 0) { redV[wv] = v; redI[wv] = idx; }
            __syncthreads();
            if (t == 0) {
                float bv = redV[0]; int bi = redI[0];
                for (int ww = 1; ww < 16; ++ww)
                    if (redV[ww] > bv || (redV[ww] == bv && redI[ww] < bi)) { bv = redV[ww]; bi = redI[ww]; }
                maxvL = bv; amaxL = bi;
            }
            __syncthreads();
            float e = expf(z - maxvL);
            #pragma unroll
            for (int off = 1; off < 64; off <<= 1) e += __shfl_xor(e, off);
            if (ln == 0) redA[wv] = e;
            __syncthreads();
            if (t == 0) {
                float ssum = 0.f;
                for (int ww = 0; ww < 16; ++ww) ssum += redA[ww];
                logSL = logf(ssum);
            }
            __syncthreads();
            if (t < NN) {
                float lp = fmaxf(z - maxvL - logSL, LP_FLOOR);
                __builtin_nontemporal_store(lp, &out[out_lp_base + (size_t)s * NN + t]);
            }
            if (t == 0) {
                __builtin_nontemporal_store((float)amaxL, &out[act_base + s]);
                maskF[amaxL] = NEGINF;
                curL = amaxL;
            }
        }
        __syncthreads();
    }
#undef STAGE_CHUNK
}

// ---------------- fp32 fallback (round-2 kernel, validated) ----------------
__global__ __launch_bounds__(1024) void ar_decoder_f32(
    const float* __restrict__ emb, const float* __restrict__ Wn,
    const float* __restrict__ Wf, const float* __restrict__ Wc,
    const float* __restrict__ Wo, const int* __restrict__ nsp,
    float* __restrict__ out)
{
    const int b = blockIdx.x;
    const int t = threadIdx.x;
    const int S = nsp[0];
    const float*  E  = emb + (size_t)b * (NN * DD);
    const float4* E4 = (const float4*)E;

    __shared__ __align__(16) float pS[8192];
    __shared__ __align__(16) float qkT[1024];
    __shared__ __align__(16) float wsumL[HH * DD];
    __shared__ __align__(16) float maskF[NP];
    __shared__ __align__(16) float ceL[DD], qL[DD], gL[DD], fL[DD], uL[DD], fcL[DD], muL[DD], e0L[DD];
    __shared__ float mL[HH], lL[HH];
    __shared__ float redA[16], redV[16];
    __shared__ int   redI[16];
    __shared__ float maxvL, logSL;
    __shared__ int   curL, amaxL;

    {
        const int d = t & 127, strip = t >> 7;
        float acc = 0.f;
        const int n0 = strip * 125;
        for (int k = 0; k < 125; ++k) acc += E[(n0 + k) * DD + d];
        pS[strip * 128 + d] = acc;
    }
    if (t < DD) e0L[t] = E[t];
    __syncthreads();
    if (t < DD) {
        float ssum = 0.f;
        for (int k = 0; k < 8; ++k) ssum += pS[k * 128 + t];
        muL[t] = ssum * (1.0f / (float)NN);
    }
    __syncthreads();
    if (t < DD) {
        float fc = 0.f;
        for (int i = 0; i < DD; ++i)
            fc += muL[i] * Wf[i * DD + t] + e0L[i] * Wc[i * DD + t];
        fcL[t] = fc;
    }
    maskF[t] = (t == 0 || t >= NN) ? NEGINF : 0.f;
    if (t == 0) curL = 0;
    __syncthreads();

    const size_t out_lp_base = (size_t)b * S * NN;
    const size_t act_base    = (size_t)BB * S * NN + (size_t)b * S;

    for (int s = 0; s < S; ++s) {
        if (t < DD) ceL[t] = E[curL * DD + t];
        __syncthreads();
        if (t < DD) {
            float q = fcL[t];
            for (int i = 0; i < DD; ++i) q += ceL[i] * Wc[(DD + i) * DD + t];
            qL[t] = q;
        }
        __syncthreads();
        {
            const int h = t >> 7, d = t & 127;
            float v = 0.f;
            for (int k = 0; k < 16; ++k) v += Wn[d * 384 + h * 16 + k] * qL[h * 16 + k];
            qkT[(d >> 2) * 32 + h * 4 + (d & 3)] = v * SC_QK;
        }
        __syncthreads();
        {
            const int dq = t & 3, h = (t >> 2) & 7, o = t >> 5;
            float4 qk4[8];
            const float4* qkT4 = (const float4*)qkT;
            #pragma unroll
            for (int i = 0; i < 8; ++i) qk4[i] = qkT4[(i * 4 + dq) * 8 + h];
            for (int oi = 0; oi < 4; ++oi) {
                const int oe = oi * 32 + o;
                float acc[8] = {0,0,0,0,0,0,0,0};
                #pragma unroll
                for (int i = 0; i < 8; ++i) {
                    const int d4 = i * 4 + dq;
                    #pragma unroll
                    for (int j = 0; j < 8; ++j) {
                        int row = oe * 8 + j; if (row > NN - 1) row = NN - 1;
                        acc[j] += dot4(E4[row * 32 + d4], qk4[i]);
                    }
                }
                #pragma unroll
                for (int j = 0; j < 8; ++j) {
                    acc[j] += __shfl_xor(acc[j], 1);
                    acc[j] += __shfl_xor(acc[j], 2);
                }
                const int j0 = 2 * dq;
                pS[(oe * 8 + j0)     * 8 + h] = acc[j0];
                pS[(oe * 8 + j0 + 1) * 8 + h] = acc[j0 + 1];
            }
        }
        __syncthreads();
        {
            const int w = t >> 6, lane = t & 63;
            const int h = w & 7, half = (w >> 3) * 512;
            float m = NEGINF;
            for (int k = 0; k < 8; ++k) {
                const int n = half + k * 64 + lane;
                m = fmaxf(m, pS[n * 8 + h] + maskF[n]);
            }
            for (int off = 32; off > 0; off >>= 1) m = fmaxf(m, __shfl_xor(m, off));
            if (lane == 0) redA[w] = m;
        }
        __syncthreads();
        if (t < HH) mL[t] = fmaxf(redA[t], redA[8 + t]);
        __syncthreads();
        {
            float4* pS4 = (float4*)pS;
            float4 a = pS4[t * 2], c = pS4[t * 2 + 1];
            const float mf = maskF[t];
            a.x = expf(a.x + mf - mL[0]); a.y = expf(a.y + mf - mL[1]);
            a.z = expf(a.z + mf - mL[2]); a.w = expf(a.w + mf - mL[3]);
            c.x = expf(c.x + mf - mL[4]); c.y = expf(c.y + mf - mL[5]);
            c.z = expf(c.z + mf - mL[6]); c.w = expf(c.w + mf - mL[7]);
            pS4[t * 2] = a; pS4[t * 2 + 1] = c;
        }
        __syncthreads();
        {
            const int w = t >> 6, lane = t & 63;
            const int h = w & 7, half = (w >> 3) * 512;
            float sum = 0.f;
            for (int k = 0; k < 8; ++k) sum += pS[(half + k * 64 + lane) * 8 + h];
            for (int off = 32; off > 0; off >>= 1) sum += __shfl_xor(sum, off);
            if (lane == 0) redA[w] = sum;
        }
        __syncthreads();
        if (t < HH) lL[t] = redA[t] + redA[8 + t];
        __syncthreads();
        {
            float4 acc[8];
            const int d4 = t & 31, nq = t >> 5;
            #pragma unroll
            for (int h = 0; h < 8; ++h) acc[h] = make_float4(0, 0, 0, 0);
            const float4* pS4 = (const float4*)pS;
            for (int k = 0; k < 32; ++k) {
                const int n = nq * 32 + k;
                const int row = (n > NN - 1) ? NN - 1 : n;
                float4 e4 = E4[row * 32 + d4];
                float4 pa = pS4[n * 2], pb = pS4[n * 2 + 1];
                acc[0] = fma4(pa.x, e4, acc[0]); acc[1] = fma4(pa.y, e4, acc[1]);
                acc[2] = fma4(pa.z, e4, acc[2]); acc[3] = fma4(pa.w, e4, acc[3]);
                acc[4] = fma4(pb.x, e4, acc[4]); acc[5] = fma4(pb.y, e4, acc[5]);
                acc[6] = fma4(pb.z, e4, acc[6]); acc[7] = fma4(pb.w, e4, acc[7]);
            }
            __syncthreads();
            #pragma unroll
            for (int h = 0; h < 8; ++h) {
                acc[h].x += __shfl_xor(acc[h].x, 32);
                acc[h].y += __shfl_xor(acc[h].y, 32);
                acc[h].z += __shfl_xor(acc[h].z, 32);
                acc[h].w += __shfl_xor(acc[h].w, 32);
            }
            const int w = t >> 6, lane = t & 63;
            float4* red4 = (float4*)pS;
            for (int rh = 0; rh < 2; ++rh) {
                if (lane < 32) {
                    #pragma unroll
                    for (int hh = 0; hh < 4; ++hh)
                        red4[(w * 4 + hh) * 32 + d4] = acc[rh * 4 + hh];
                }
                __syncthreads();
                if (t < 512) {
                    const int hh = t >> 7, d = t & 127;
                    float ssum = 0.f;
                    for (int ww = 0; ww < 16; ++ww) ssum += pS[(ww * 4 + hh) * 128 + d];
                    wsumL[(rh * 4 + hh) * DD + d] = ssum;
                }
                __syncthreads();
            }
        }
        if (t < DD) {
            const int h = t >> 4;
            float g = 0.f;
            for (int d = 0; d < DD; ++d) g += wsumL[h * DD + d] * Wn[d * 384 + DD + t];
            gL[t] = g / lL[h];
        }
        __syncthreads();
        if (t < DD) {
            float f = 0.f;
            for (int i = 0; i < DD; ++i) f += gL[i] * Wo[i * DD + t];
            fL[t] = f;
        }
        __syncthreads();
        if (t < DD) {
            float u = 0.f;
            for (int k = 0; k < DD; ++k) u += Wn[t * 384 + 256 + k] * fL[k];
            uL[t] = u * SC_LG;
        }
        __syncthreads();
        {
            const int row = (t > NN - 1) ? NN - 1 : t;
            float lg = 0.f;
            const float4* uL4 = (const float4*)uL;
            for (int d4 = 0; d4 < 32; ++d4) lg += dot4(E4[row * 32 + d4], uL4[d4]);
            const float z = CLIPV * tanhf(lg) + maskF[t];
            float v = z; int idx = t;
            for (int off = 1; off < 64; off <<= 1) {
                float v2 = __shfl_xor(v, off);
                int   i2 = __shfl_xor(idx, off);
                if (v2 > v || (v2 == v && i2 < idx)) { v = v2; idx = i2; }
            }
            const int w = t >> 6, lane = t & 63;
            if (lane == 0) { redV[w] = v; redI[w] = idx; }
            __syncthreads();
            if (t == 0) {
                float bv = redV[0]; int bi = redI[0];
                for (int ww = 1; ww < 16; ++ww)
                    if (redV[ww] > bv || (redV[ww] == bv && redI[ww] < bi)) { bv = redV[ww]; bi = redI[ww]; }
                maxvL = bv; amaxL = bi;
            }
            __syncthreads();
            float e = expf(z - maxvL);
            for (int off = 1; off < 64; off <<= 1) e += __shfl_xor(e, off);
            if (lane == 0) redA[w] = e;
            __syncthreads();
            if (t == 0) {
                float ssum = 0.f;
                for (int ww = 0; ww < 16; ++ww) ssum += redA[ww];
                logSL = logf(ssum);
            }
            __syncthreads();
            if (t < NN) {
                float lp = z - maxvL - logSL;
                out[out_lp_base + (size_t)s * NN + t] = fmaxf(lp, LP_FLOOR);
            }
            if (t == 0) {
                out[act_base + s] = (float)amaxL;
                maskF[amaxL] = NEGINF;
                curL = amaxL;
            }
        }
        __syncthreads();
    }
}

extern "C" void kernel_launch(void* const* d_in, const int* in_sizes, int n_in,
                              void* d_out, int out_size, void* d_ws, size_t ws_size,
                              hipStream_t stream) {
    const float* emb = (const float*)d_in[0];
    const float* Wn  = (const float*)d_in[1];
    const float* Wf  = (const float*)d_in[2];
    const float* Wc  = (const float*)d_in[3];
    const float* Wo  = (const float*)d_in[4];
    const int*   nsp = (const int*)d_in[5];
    const size_t need = (size_t)BB * 1024 * DD * sizeof(unsigned short);  // 67.1 MB padded
    if (ws_size >= need) {
        unsigned short* ebf = (unsigned short*)d_ws;
        const int nunits = BB * 1024 * 16;              // 8-bf16 units
        conv_bf16_pad<<<dim3(nunits / 256), dim3(256), 0, stream>>>(emb, ebf);
        ar_decoder_bf16<<<dim3(BB), dim3(1024), 0, stream>>>(emb, ebf, Wn, Wf, Wc, Wo, nsp, (float*)d_out);
    } else {
        ar_decoder_f32<<<dim3(BB), dim3(1024), 0, stream>>>(emb, Wn, Wf, Wc, Wo, nsp, (float*)d_out);
    }
}

// Round 5
// 4694.711 us; speedup vs baseline: 1.3347x; 1.3347x over previous
//
#include <hip/hip_runtime.h>
#include <math.h>

#define BB 256
#define NN 1000
#define DD 128
#define HH 8
#define NP 1024
#define CHROWS 128
#define CLIPV 10.0f
#define SC_QK 0.25f                       // 1/sqrt(16)
#define SC_LG 0.08838834764831845f        // 1/sqrt(128)
#define NEGINF (-INFINITY)
#define LP_FLOOR (-3.0e38f)               // finite stand-in for -inf in output

typedef float  fx4 __attribute__((ext_vector_type(4)));
typedef unsigned short usx4 __attribute__((ext_vector_type(4)));

__device__ __forceinline__ float dot4(float4 a, float4 b) {
    return fmaf(a.x, b.x, fmaf(a.y, b.y, fmaf(a.z, b.z, a.w * b.w)));
}
__device__ __forceinline__ float4 fma4(float p, float4 e, float4 a) {
    a.x = fmaf(p, e.x, a.x); a.y = fmaf(p, e.y, a.y);
    a.z = fmaf(p, e.z, a.z); a.w = fmaf(p, e.w, a.w);
    return a;
}
__device__ __forceinline__ void bf2f(unsigned int u, float& a, float& b) {
    union { unsigned int i; float f; } lo, hi;
    lo.i = u << 16; hi.i = u & 0xffff0000u;
    a = lo.f; b = hi.f;
}
__device__ __forceinline__ unsigned short f2bf_rne(float x) {
    union { float f; unsigned int u; } v; v.f = x;
    unsigned int r = v.u + 0x7FFFu + ((v.u >> 16) & 1u);
    return (unsigned short)(r >> 16);
}
// async global->LDS, 16B per lane; LDS dest is wave-uniform base + lane*16
__device__ __forceinline__ void gl_lds16(const unsigned short* g, unsigned short* l) {
    __builtin_amdgcn_global_load_lds(
        (__attribute__((address_space(1))) void*)(g),
        (__attribute__((address_space(3))) void*)(l), 16, 0, 0);
}

// ---------------- fp32 emb -> bf16 scratch copy, padded to 1024 rows ----------------
__global__ __launch_bounds__(256) void conv_bf16_pad(const float* __restrict__ emb,
                                                     unsigned short* __restrict__ ebf) {
    const int idx = blockIdx.x * 256 + threadIdx.x;     // one 8-bf16 unit (16B out)
    const int b   = idx >> 14;                          // / (1024*16)
    const int row = (idx >> 4) & 1023;
    const int k8  = idx & 15;
    uint4 o = make_uint4(0u, 0u, 0u, 0u);               // pad rows -> zeros
    if (row < NN) {
        const float* p = emb + ((size_t)b * NN + row) * DD + k8 * 8;
        fx4 f0 = __builtin_nontemporal_load((const fx4*)p);
        fx4 f1 = __builtin_nontemporal_load((const fx4*)(p + 4));
        o.x = ((unsigned)f2bf_rne(f0.y) << 16) | f2bf_rne(f0.x);
        o.y = ((unsigned)f2bf_rne(f0.w) << 16) | f2bf_rne(f0.z);
        o.z = ((unsigned)f2bf_rne(f1.y) << 16) | f2bf_rne(f1.x);
        o.w = ((unsigned)f2bf_rne(f1.w) << 16) | f2bf_rne(f1.z);
    }
    *(uint4*)(ebf + (size_t)idx * 8) = o;
}

// ---------------- main decoder ----------------
// The 3 sweeps per step read the SAME 8 chunks (32KB each). Alternating sweep
// direction reuses the 3 chunks still resident in the rotating buffers at
// sweep entry: only 5/8 chunks staged per sweep (chains across sweeps AND
// steps) => 37.5% fetch cut. Buffer map is static: buf = chunk % 3.
//   fwd: resident {0,1,2}; phases 2..6 stage chunk i+1 -> bufs 0,1,2,0,1
//   rev: resident {5,6,7}; phases 2..6 stage chunk 6-i -> bufs 1,0,2,1,0
// Each staged buffer was last read two phases (two barriers) earlier.
// Plain __syncthreads() per phase (drains vmcnt) - validated r2 machinery;
// counted-vmcnt pipelining measured neutral here (r3), so not used.
__global__ __launch_bounds__(1024, 4) void ar_decoder_bf16(
    const float* __restrict__ emb,            // [B][N][D] fp32 (small reads only)
    const unsigned short* __restrict__ embbf, // [B][1024][D] bf16 padded (sweeps)
    const float* __restrict__ Wn,    // [D][3D]  (gk | gv | lk columns)
    const float* __restrict__ Wf,    // [D][D]
    const float* __restrict__ Wc,    // [2D][D]
    const float* __restrict__ Wo,    // [D][D]
    const int*  __restrict__ nsp,    // num_steps
    float* __restrict__ out)         // [B][S][N] log_p then [B][S] actions (as float)
{
    const int b = blockIdx.x;
    const int t = threadIdx.x;
    const int S = nsp[0];
    const float* E  = emb + (size_t)b * (NN * DD);
    const unsigned short* Ebf = embbf + (size_t)b * (1024 * DD);
    const int wv = t >> 6, ln = t & 63;

    __shared__ __align__(16) unsigned short ebuf[3][CHROWS * DD];  // 3 x 32KB staging
    __shared__ __align__(16) float pS[8192];       // scores/p [n][8]; also wsum scratch
    __shared__ __align__(16) float qkT[HH * 132];  // qk [h][132] padded
    __shared__ __align__(16) float wsumL[HH * DD];
    __shared__ __align__(16) float maskF[NP];      // 0 = live, -inf = visited/pad
    __shared__ __align__(16) float zS[NP];         // clipped+masked logits
    __shared__ __align__(16) float ceL[DD], qL[DD], gL[DD], fL[DD], uL[DD];
    __shared__ __align__(16) float fcL[DD], muL[DD], e0L[DD];
    __shared__ __align__(16) float wredM[128], wredS[128];
    __shared__ float mL[HH], lL[HH];
    __shared__ float redA[16], redV[16];
    __shared__ int   redI[16];
    __shared__ float maxvL, logSL;
    __shared__ int   curL, amaxL;

    // stage one 128-row chunk (32KB) of Ebf into ebuf[bi]; all 16 waves, 2KB each
#define STAGE_CHUNK(cidx, bi) do {                                             \
        const unsigned short* _s = Ebf + (size_t)(cidx) * (CHROWS * DD);       \
        unsigned short* _d = &ebuf[bi][0];                                     \
        gl_lds16(_s + wv * 512 + ln * 8,        _d + wv * 512);                \
        gl_lds16(_s + (16 + wv) * 512 + ln * 8, _d + (16 + wv) * 512);         \
    } while (0)
    // stage at phase i the chunk needed at phase i+1 (none resident-side)
#define SWEEP_STAGE(i, f) do {                                                 \
        if ((i) >= 2 && (i) <= 6) {                                            \
            const int _tc = (f) ? (i) + 1 : 6 - (i);                           \
            STAGE_CHUNK(_tc, _tc % 3);                                         \
        }                                                                      \
    } while (0)

    bool fwd = true;

    // pre-stage chunks 0,1,2 for the first (forward) sweep; the prologue's
    // __syncthreads barriers drain vmcnt before first use.
    STAGE_CHUNK(0, 0);
    STAGE_CHUNK(1, 1);
    STAGE_CHUNK(2, 2);

    // ---------------- prologue ----------------
    {   // mean over nodes (8 strips of 125)
        const int d = t & 127, strip = t >> 7;
        float acc = 0.f;
        const int n0 = strip * 125;
        for (int k = 0; k < 125; ++k) acc += E[(n0 + k) * DD + d];
        pS[strip * 128 + d] = acc;
    }
    if (t < DD) e0L[t] = E[t];
    __syncthreads();
    if (t < DD) {
        float ssum = 0.f;
        for (int k = 0; k < 8; ++k) ssum += pS[k * 128 + t];
        muL[t] = ssum * (1.0f / (float)NN);
    }
    __syncthreads();
    if (t < DD) {
        float fc = 0.f;
        for (int i = 0; i < DD; ++i)
            fc += muL[i] * Wf[i * DD + t] + e0L[i] * Wc[i * DD + t];
        fcL[t] = fc;
    }
    maskF[t] = (t == 0 || t >= NN) ? NEGINF : 0.f;
    if (t == 0) curL = 0;
    __syncthreads();

    const size_t out_lp_base = (size_t)b * S * NN;
    const size_t act_base    = (size_t)BB * S * NN + (size_t)b * S;

    for (int s = 0; s < S; ++s) {
        // (0) current node embedding (fp32, exact)
        if (t < DD) ceL[t] = E[curL * DD + t];
        __syncthreads();
        // (1) q = fc + cur_emb @ Wc_bottom  (8-way k-split per output)
        {
            const int d = t >> 3, p = t & 7;
            const int i0 = p * 16;
            float q = 0.f;
            #pragma unroll
            for (int i = 0; i < 16; ++i)
                q += ceL[i0 + i] * Wc[(DD + i0 + i) * DD + d];
            q += __shfl_xor(q, 1);
            q += __shfl_xor(q, 2);
            q += __shfl_xor(q, 4);
            if (p == 0) qL[d] = q + fcL[d];
        }
        __syncthreads();
        // (2) qk[h][d] = 0.25 * sum_k Wk[d][h*16+k] * q[h*16+k]
        {
            const int h = t >> 7, d = t & 127;
            float v = 0.f;
            for (int k = 0; k < 16; ++k)
                v += Wn[d * 384 + h * 16 + k] * qL[h * 16 + k];
            qkT[h * 132 + d] = v * SC_QK;
        }
        __syncthreads();
        // (3) scores sweep (alternating direction, 3-chunk reuse)
        {
            const int dq = t & 3, h = (t >> 2) & 7, o2 = t >> 5;   // o2 in 0..31
            float4 qk4[8];                 // chunks c = dq+4m, elems [c*8, c*8+8)
            #pragma unroll
            for (int m = 0; m < 4; ++m) {
                const float* qp = &qkT[h * 132 + (dq + 4 * m) * 8];
                qk4[2 * m]     = *(const float4*)(qp);
                qk4[2 * m + 1] = *(const float4*)(qp + 4);
            }
            float mloc = NEGINF;
            for (int i = 0; i < 8; ++i) {
                const int ck = fwd ? i : 7 - i;
                SWEEP_STAGE(i, fwd);
                const unsigned short* Eb = &ebuf[ck % 3][0];
                float acc[4];
                #pragma unroll
                for (int j = 0; j < 4; ++j) acc[j] = 0.f;
                #pragma unroll
                for (int j = 0; j < 4; ++j) {
                    const int r = o2 * 4 + j;
                    const uint4* rp = (const uint4*)(Eb + r * DD);
                    #pragma unroll
                    for (int m = 0; m < 4; ++m) {
                        uint4 u = rp[dq + 4 * m];
                        float e0,e1,e2,e3,e4,e5,e6,e7;
                        bf2f(u.x, e0, e1); bf2f(u.y, e2, e3);
                        bf2f(u.z, e4, e5); bf2f(u.w, e6, e7);
                        const float4 qa = qk4[2 * m], qb = qk4[2 * m + 1];
                        acc[j] = fmaf(e0, qa.x, fmaf(e1, qa.y, fmaf(e2, qa.z, fmaf(e3, qa.w, acc[j]))));
                        acc[j] = fmaf(e4, qb.x, fmaf(e5, qb.y, fmaf(e6, qb.z, fmaf(e7, qb.w, acc[j]))));
                    }
                }
                #pragma unroll
                for (int j = 0; j < 4; ++j) {
                    acc[j] += __shfl_xor(acc[j], 1);
                    acc[j] += __shfl_xor(acc[j], 2);
                }
                const int nb = ck * 128 + o2 * 4;
                pS[(nb + dq) * 8 + h] = acc[dq];
                #pragma unroll
                for (int j = 0; j < 4; ++j)
                    mloc = fmaxf(mloc, acc[j] + maskF[nb + j]);   // pad rows -> -inf
                __syncthreads();
            }
            fwd = !fwd;
            // reduce over lanes sharing h (bits 0,1,5)
            mloc = fmaxf(mloc, __shfl_xor(mloc, 1));
            mloc = fmaxf(mloc, __shfl_xor(mloc, 2));
            mloc = fmaxf(mloc, __shfl_xor(mloc, 32));
            if ((t & 35) == 0) wredM[wv * 8 + h] = mloc;
        }
        __syncthreads();
        if (t < HH) {
            float m = wredM[t];
            for (int w = 1; w < 16; ++w) m = fmaxf(m, wredM[w * 8 + t]);
            mL[t] = m;
        }
        __syncthreads();
        // (4) p = exp(s + mask - m) in place + fused per-h partial sums
        {
            float4* pS4 = (float4*)pS;
            float4 a = pS4[t * 2], c = pS4[t * 2 + 1];
            const float mf = maskF[t];
            a.x = expf(a.x + mf - mL[0]); a.y = expf(a.y + mf - mL[1]);
            a.z = expf(a.z + mf - mL[2]); a.w = expf(a.w + mf - mL[3]);
            c.x = expf(c.x + mf - mL[4]); c.y = expf(c.y + mf - mL[5]);
            c.z = expf(c.z + mf - mL[6]); c.w = expf(c.w + mf - mL[7]);
            pS4[t * 2] = a; pS4[t * 2 + 1] = c;
            #pragma unroll
            for (int off = 1; off < 64; off <<= 1) {
                a.x += __shfl_xor(a.x, off); a.y += __shfl_xor(a.y, off);
                a.z += __shfl_xor(a.z, off); a.w += __shfl_xor(a.w, off);
                c.x += __shfl_xor(c.x, off); c.y += __shfl_xor(c.y, off);
                c.z += __shfl_xor(c.z, off); c.w += __shfl_xor(c.w, off);
            }
            if (ln == 0) {
                ((float4*)wredS)[wv * 2] = a;
                ((float4*)wredS)[wv * 2 + 1] = c;
            }
        }
        __syncthreads();
        if (t < HH) {
            float ssum = 0.f;
            for (int w = 0; w < 16; ++w) ssum += wredS[w * 8 + t];
            lL[t] = ssum;
        }
        // (5) wsum sweep (alternating direction, 3-chunk reuse)
        {
            const int d8 = t & 15, g2 = (t >> 4) & 3, gh = wv & 7, hp = t >> 9;
            float acc[4][8];
            #pragma unroll
            for (int hh = 0; hh < 4; ++hh)
                #pragma unroll
                for (int i = 0; i < 8; ++i) acc[hh][i] = 0.f;
            const float4* pS4 = (const float4*)pS;
            for (int i = 0; i < 8; ++i) {
                const int ck = fwd ? i : 7 - i;
                SWEEP_STAGE(i, fwd);
                const unsigned short* Eb = &ebuf[ck % 3][0];
                #pragma unroll
                for (int k2 = 0; k2 < 4; ++k2) {
                    const int r = k2 * 32 + gh * 4 + g2;
                    const int n = ck * 128 + r;
                    uint4 u = *(const uint4*)(Eb + r * DD + d8 * 8);
                    float e[8];
                    bf2f(u.x, e[0], e[1]); bf2f(u.y, e[2], e[3]);
                    bf2f(u.z, e[4], e[5]); bf2f(u.w, e[6], e[7]);
                    const float4 p4 = pS4[n * 2 + hp];
                    #pragma unroll
                    for (int i2 = 0; i2 < 8; ++i2) {
                        acc[0][i2] = fmaf(p4.x, e[i2], acc[0][i2]);
                        acc[1][i2] = fmaf(p4.y, e[i2], acc[1][i2]);
                        acc[2][i2] = fmaf(p4.z, e[i2], acc[2][i2]);
                        acc[3][i2] = fmaf(p4.w, e[i2], acc[3][i2]);
                    }
                }
                __syncthreads();
            }
            fwd = !fwd;
            // reduce over g2 (lane bits 4,5)
            #pragma unroll
            for (int hh = 0; hh < 4; ++hh)
                #pragma unroll
                for (int i = 0; i < 8; ++i) {
                    acc[hh][i] += __shfl_xor(acc[hh][i], 16);
                    acc[hh][i] += __shfl_xor(acc[hh][i], 32);
                }
            if (ln < 16) {   // ln == d8, g2 == 0
                #pragma unroll
                for (int hh = 0; hh < 4; ++hh) {
                    float4* dst = (float4*)&pS[gh * 1024 + (hp * 4 + hh) * 128 + d8 * 8];
                    dst[0] = make_float4(acc[hh][0], acc[hh][1], acc[hh][2], acc[hh][3]);
                    dst[1] = make_float4(acc[hh][4], acc[hh][5], acc[hh][6], acc[hh][7]);
                }
            }
            __syncthreads();
            {
                const int h = t >> 7, d = t & 127;
                float ssum = 0.f;
                #pragma unroll
                for (int g = 0; g < 8; ++g) ssum += pS[g * 1024 + h * 128 + d];
                wsumL[h * DD + d] = ssum;
            }
            __syncthreads();
        }
        // (6) g[c] = (wsum[h]·Wv[:,c]) / l[h]   (8-way d-split)
        {
            const int c = t >> 3, p = t & 7, h = c >> 4;
            const int d0 = p * 16;
            float g = 0.f;
            #pragma unroll
            for (int i = 0; i < 16; ++i)
                g += wsumL[h * DD + d0 + i] * Wn[(d0 + i) * 384 + DD + c];
            g += __shfl_xor(g, 1);
            g += __shfl_xor(g, 2);
            g += __shfl_xor(g, 4);
            if (p == 0) gL[c] = g / lL[h];
        }
        __syncthreads();
        // (7) f = g @ W_out   (8-way i-split)
        {
            const int d = t >> 3, p = t & 7;
            const int i0 = p * 16;
            float f = 0.f;
            #pragma unroll
            for (int i = 0; i < 16; ++i)
                f += gL[i0 + i] * Wo[(i0 + i) * DD + d];
            f += __shfl_xor(f, 1);
            f += __shfl_xor(f, 2);
            f += __shfl_xor(f, 4);
            if (p == 0) fL[d] = f;
        }
        __syncthreads();
        // (8) u[d] = sc * sum_k Wl[d][k] * f[k]   (8-way k-split)
        {
            const int d = t >> 3, p = t & 7;
            const int k0 = p * 16;
            float u = 0.f;
            #pragma unroll
            for (int k = 0; k < 16; ++k)
                u += Wn[d * 384 + 256 + k0 + k] * fL[k0 + k];
            u += __shfl_xor(u, 1);
            u += __shfl_xor(u, 2);
            u += __shfl_xor(u, 4);
            if (p == 0) uL[d] = u * SC_LG;
        }
        __syncthreads();
        // (9) logits sweep (alternating direction, 3-chunk reuse) -> zS
        {
            const int q8 = t & 7, rr = t >> 3;   // rr in 0..127 per chunk
            const float4* uL4 = (const float4*)uL;
            const float4 ua0 = uL4[q8 * 2],       ub0 = uL4[q8 * 2 + 1];
            const float4 ua1 = uL4[(q8 + 8) * 2], ub1 = uL4[(q8 + 8) * 2 + 1];
            for (int i = 0; i < 8; ++i) {
                const int ck = fwd ? i : 7 - i;
                SWEEP_STAGE(i, fwd);
                const unsigned short* Eb = &ebuf[ck % 3][0];
                const int n = ck * 128 + rr;
                uint4 u0 = *(const uint4*)(Eb + rr * DD + q8 * 8);
                uint4 u1 = *(const uint4*)(Eb + rr * DD + (q8 + 8) * 8);
                float e0,e1,e2,e3,e4,e5,e6,e7;
                bf2f(u0.x, e0, e1); bf2f(u0.y, e2, e3);
                bf2f(u0.z, e4, e5); bf2f(u0.w, e6, e7);
                float lg;
                lg = fmaf(e0, ua0.x, fmaf(e1, ua0.y, fmaf(e2, ua0.z, e3 * ua0.w)));
                lg = fmaf(e4, ub0.x, fmaf(e5, ub0.y, fmaf(e6, ub0.z, fmaf(e7, ub0.w, lg))));
                bf2f(u1.x, e0, e1); bf2f(u1.y, e2, e3);
                bf2f(u1.z, e4, e5); bf2f(u1.w, e6, e7);
                lg = fmaf(e0, ua1.x, fmaf(e1, ua1.y, fmaf(e2, ua1.z, fmaf(e3, ua1.w, lg))));
                lg = fmaf(e4, ub1.x, fmaf(e5, ub1.y, fmaf(e6, ub1.z, fmaf(e7, ub1.w, lg))));
                lg += __shfl_xor(lg, 1);
                lg += __shfl_xor(lg, 2);
                lg += __shfl_xor(lg, 4);
                if (q8 == 0)
                    zS[n] = (n < NN) ? (CLIPV * tanhf(lg) + maskF[n]) : NEGINF;
                __syncthreads();
            }
            fwd = !fwd;
        }
        // (10) log-softmax + argmax from zS, output, state update
        {
            const float z = zS[t];
            float v = z; int idx = t;
            #pragma unroll
            for (int off = 1; off < 64; off <<= 1) {
                float v2 = __shfl_xor(v, off);
                int   i2 = __shfl_xor(idx, off);
                if (v2 > v || (v2 == v && i2 < idx)) { v = v2; idx = i2; }
            }
            if (ln == 0) { redV[wv] = v; redI[wv] = idx; }
            __syncthreads();
            if (t == 0) {
                float bv = redV[0]; int bi = redI[0];
                for (int ww = 1; ww < 16; ++ww)
                    if (redV[ww] > bv || (redV[ww] == bv && redI[ww] < bi)) { bv = redV[ww]; bi = redI[ww]; }
                maxvL = bv; amaxL = bi;
            }
            __syncthreads();
            float e = expf(z - maxvL);
            #pragma unroll
            for (int off = 1; off < 64; off <<= 1) e += __shfl_xor(e, off);
            if (ln == 0) redA[wv] = e;
            __syncthreads();
            if (t == 0) {
                float ssum = 0.f;
                for (int ww = 0; ww < 16; ++ww) ssum += redA[ww];
                logSL = logf(ssum);
            }
            __syncthreads();
            if (t < NN) {
                float lp = fmaxf(z - maxvL - logSL, LP_FLOOR);
                __builtin_nontemporal_store(lp, &out[out_lp_base + (size_t)s * NN + t]);
            }
            if (t == 0) {
                __builtin_nontemporal_store((float)amaxL, &out[act_base + s]);
                maskF[amaxL] = NEGINF;
                curL = amaxL;
            }
        }
        __syncthreads();
    }
#undef SWEEP_STAGE
#undef STAGE_CHUNK
}

// ---------------- fp32 fallback (round-2 kernel, validated) ----------------
__global__ __launch_bounds__(1024) void ar_decoder_f32(
    const float* __restrict__ emb, const float* __restrict__ Wn,
    const float* __restrict__ Wf, const float* __restrict__ Wc,
    const float* __restrict__ Wo, const int* __restrict__ nsp,
    float* __restrict__ out)
{
    const int b = blockIdx.x;
    const int t = threadIdx.x;
    const int S = nsp[0];
    const float*  E  = emb + (size_t)b * (NN * DD);
    const float4* E4 = (const float4*)E;

    __shared__ __align__(16) float pS[8192];
    __shared__ __align__(16) float qkT[1024];
    __shared__ __align__(16) float wsumL[HH * DD];
    __shared__ __align__(16) float maskF[NP];
    __shared__ __align__(16) float ceL[DD], qL[DD], gL[DD], fL[DD], uL[DD], fcL[DD], muL[DD], e0L[DD];
    __shared__ float mL[HH], lL[HH];
    __shared__ float redA[16], redV[16];
    __shared__ int   redI[16];
    __shared__ float maxvL, logSL;
    __shared__ int   curL, amaxL;

    {
        const int d = t & 127, strip = t >> 7;
        float acc = 0.f;
        const int n0 = strip * 125;
        for (int k = 0; k < 125; ++k) acc += E[(n0 + k) * DD + d];
        pS[strip * 128 + d] = acc;
    }
    if (t < DD) e0L[t] = E[t];
    __syncthreads();
    if (t < DD) {
        float ssum = 0.f;
        for (int k = 0; k < 8; ++k) ssum += pS[k * 128 + t];
        muL[t] = ssum * (1.0f / (float)NN);
    }
    __syncthreads();
    if (t < DD) {
        float fc = 0.f;
        for (int i = 0; i < DD; ++i)
            fc += muL[i] * Wf[i * DD + t] + e0L[i] * Wc[i * DD + t];
        fcL[t] = fc;
    }
    maskF[t] = (t == 0 || t >= NN) ? NEGINF : 0.f;
    if (t == 0) curL = 0;
    __syncthreads();

    const size_t out_lp_base = (size_t)b * S * NN;
    const size_t act_base    = (size_t)BB * S * NN + (size_t)b * S;

    for (int s = 0; s < S; ++s) {
        if (t < DD) ceL[t] = E[curL * DD + t];
        __syncthreads();
        if (t < DD) {
            float q = fcL[t];
            for (int i = 0; i < DD; ++i) q += ceL[i] * Wc[(DD + i) * DD + t];
            qL[t] = q;
        }
        __syncthreads();
        {
            const int h = t >> 7, d = t & 127;
            float v = 0.f;
            for (int k = 0; k < 16; ++k) v += Wn[d * 384 + h * 16 + k] * qL[h * 16 + k];
            qkT[(d >> 2) * 32 + h * 4 + (d & 3)] = v * SC_QK;
        }
        __syncthreads();
        {
            const int dq = t & 3, h = (t >> 2) & 7, o = t >> 5;
            float4 qk4[8];
            const float4* qkT4 = (const float4*)qkT;
            #pragma unroll
            for (int i = 0; i < 8; ++i) qk4[i] = qkT4[(i * 4 + dq) * 8 + h];
            for (int oi = 0; oi < 4; ++oi) {
                const int oe = oi * 32 + o;
                float acc[8] = {0,0,0,0,0,0,0,0};
                #pragma unroll
                for (int i = 0; i < 8; ++i) {
                    const int d4 = i * 4 + dq;
                    #pragma unroll
                    for (int j = 0; j < 8; ++j) {
                        int row = oe * 8 + j; if (row > NN - 1) row = NN - 1;
                        acc[j] += dot4(E4[row * 32 + d4], qk4[i]);
                    }
                }
                #pragma unroll
                for (int j = 0; j < 8; ++j) {
                    acc[j] += __shfl_xor(acc[j], 1);
                    acc[j] += __shfl_xor(acc[j], 2);
                }
                const int j0 = 2 * dq;
                pS[(oe * 8 + j0)     * 8 + h] = acc[j0];
                pS[(oe * 8 + j0 + 1) * 8 + h] = acc[j0 + 1];
            }
        }
        __syncthreads();
        {
            const int w = t >> 6, lane = t & 63;
            const int h = w & 7, half = (w >> 3) * 512;
            float m = NEGINF;
            for (int k = 0; k < 8; ++k) {
                const int n = half + k * 64 + lane;
                m = fmaxf(m, pS[n * 8 + h] + maskF[n]);
            }
            for (int off = 32; off > 0; off >>= 1) m = fmaxf(m, __shfl_xor(m, off));
            if (lane == 0) redA[w] = m;
        }
        __syncthreads();
        if (t < HH) mL[t] = fmaxf(redA[t], redA[8 + t]);
        __syncthreads();
        {
            float4* pS4 = (float4*)pS;
            float4 a = pS4[t * 2], c = pS4[t * 2 + 1];
            const float mf = maskF[t];
            a.x = expf(a.x + mf - mL[0]); a.y = expf(a.y + mf - mL[1]);
            a.z = expf(a.z + mf - mL[2]); a.w = expf(a.w + mf - mL[3]);
            c.x = expf(c.x + mf - mL[4]); c.y = expf(c.y + mf - mL[5]);
            c.z = expf(c.z + mf - mL[6]); c.w = expf(c.w + mf - mL[7]);
            pS4[t * 2] = a; pS4[t * 2 + 1] = c;
        }
        __syncthreads();
        {
            const int w = t >> 6, lane = t & 63;
            const int h = w & 7, half = (w >> 3) * 512;
            float sum = 0.f;
            for (int k = 0; k < 8; ++k) sum += pS[(half + k * 64 + lane) * 8 + h];
            for (int off = 32; off > 0; off >>= 1) sum += __shfl_xor(sum, off);
            if (lane == 0) redA[w] = sum;
        }
        __syncthreads();
        if (t < HH) lL[t] = redA[t] + redA[8 + t];
        __syncthreads();
        {
            float4 acc[8];
            const int d4 = t & 31, nq = t >> 5;
            #pragma unroll
            for (int h = 0; h < 8; ++h) acc[h] = make_float4(0, 0, 0, 0);
            const float4* pS4 = (const float4*)pS;
            for (int k = 0; k < 32; ++k) {
                const int n = nq * 32 + k;
                const int row = (n > NN - 1) ? NN - 1 : n;
                float4 e4 = E4[row * 32 + d4];
                float4 pa = pS4[n * 2], pb = pS4[n * 2 + 1];
                acc[0] = fma4(pa.x, e4, acc[0]); acc[1] = fma4(pa.y, e4, acc[1]);
                acc[2] = fma4(pa.z, e4, acc[2]); acc[3] = fma4(pa.w, e4, acc[3]);
                acc[4] = fma4(pb.x, e4, acc[4]); acc[5] = fma4(pb.y, e4, acc[5]);
                acc[6] = fma4(pb.z, e4, acc[6]); acc[7] = fma4(pb.w, e4, acc[7]);
            }
            __syncthreads();
            #pragma unroll
            for (int h = 0; h < 8; ++h) {
                acc[h].x += __shfl_xor(acc[h].x, 32);
                acc[h].y += __shfl_xor(acc[h].y, 32);
                acc[h].z += __shfl_xor(acc[h].z, 32);
                acc[h].w += __shfl_xor(acc[h].w, 32);
            }
            const int w = t >> 6, lane = t & 63;
            float4* red4 = (float4*)pS;
            for (int rh = 0; rh < 2; ++rh) {
                if (lane < 32) {
                    #pragma unroll
                    for (int hh = 0; hh < 4; ++hh)
                        red4[(w * 4 + hh) * 32 + d4] = acc[rh * 4 + hh];
                }
                __syncthreads();
                if (t < 512) {
                    const int hh = t >> 7, d = t & 127;
                    float ssum = 0.f;
                    for (int ww = 0; ww < 16; ++ww) ssum += pS[(ww * 4 + hh) * 128 + d];
                    wsumL[(rh * 4 + hh) * DD + d] = ssum;
                }
                __syncthreads();
            }
        }
        if (t < DD) {
            const int h = t >> 4;
            float g = 0.f;
            for (int d = 0; d < DD; ++d) g += wsumL[h * DD + d] * Wn[d * 384 + DD + t];
            gL[t] = g / lL[h];
        }
        __syncthreads();
        if (t < DD) {
            float f = 0.f;
            for (int i = 0; i < DD; ++i) f += gL[i] * Wo[i * DD + t];
            fL[t] = f;
        }
        __syncthreads();
        if (t < DD) {
            float u = 0.f;
            for (int k = 0; k < DD; ++k) u += Wn[t * 384 + 256 + k] * fL[k];
            uL[t] = u * SC_LG;
        }
        __syncthreads();
        {
            const int row = (t > NN - 1) ? NN - 1 : t;
            float lg = 0.f;
            const float4* uL4 = (const float4*)uL;
            for (int d4 = 0; d4 < 32; ++d4) lg += dot4(E4[row * 32 + d4], uL4[d4]);
            const float z = CLIPV * tanhf(lg) + maskF[t];
            float v = z; int idx = t;
            for (int off = 1; off < 64; off <<= 1) {
                float v2 = __shfl_xor(v, off);
                int   i2 = __shfl_xor(idx, off);
                if (v2 > v || (v2 == v && i2 < idx)) { v = v2; idx = i2; }
            }
            const int w = t >> 6, lane = t & 63;
            if (lane == 0) { redV[w] = v; redI[w] = idx; }
            __syncthreads();
            if (t == 0) {
                float bv = redV[0]; int bi = redI[0];
                for (int ww = 1; ww < 16; ++ww)
                    if (redV[ww] > bv || (redV[ww] == bv && redI[ww] < bi)) { bv = redV[ww]; bi = redI[ww]; }
                maxvL = bv; amaxL = bi;
            }
            __syncthreads();
            float e = expf(z - maxvL);
            for (int off = 1; off < 64; off <<= 1) e += __shfl_xor(e, off);
            if (lane == 0) redA[w] = e;
            __syncthreads();
            if (t == 0) {
                float ssum = 0.f;
                for (int ww = 0; ww < 16; ++ww) ssum += redA[ww];
                logSL = logf(ssum);
            }
            __syncthreads();
            if (t < NN) {
                float lp = z - maxvL - logSL;
                out[out_lp_base + (size_t)s * NN + t] = fmaxf(lp, LP_FLOOR);
            }
            if (t == 0) {
                out[act_base + s] = (float)amaxL;
                maskF[amaxL] = NEGINF;
                curL = amaxL;
            }
        }
        __syncthreads();
    }
}

extern "C" void kernel_launch(void* const* d_in, const int* in_sizes, int n_in,
                              void* d_out, int out_size, void* d_ws, size_t ws_size,
                              hipStream_t stream) {
    const float* emb = (const float*)d_in[0];
    const float* Wn  = (const float*)d_in[1];
    const float* Wf  = (const float*)d_in[2];
    const float* Wc  = (const float*)d_in[3];
    const float* Wo  = (const float*)d_in[4];
    const int*   nsp = (const int*)d_in[5];
    const size_t need = (size_t)BB * 1024 * DD * sizeof(unsigned short);  // 67.1 MB padded
    if (ws_size >= need) {
        unsigned short* ebf = (unsigned short*)d_ws;
        const int nunits = BB * 1024 * 16;              // 8-bf16 units
        conv_bf16_pad<<<dim3(nunits / 256), dim3(256), 0, stream>>>(emb, ebf);
        ar_decoder_bf16<<<dim3(BB), dim3(1024), 0, stream>>>(emb, ebf, Wn, Wf, Wc, Wo, nsp, (float*)d_out);
    } else {
        ar_decoder_f32<<<dim3(BB), dim3(1024), 0, stream>>>(emb, Wn, Wf, Wc, Wo, nsp, (float*)d_out);
    }
}

// Round 9
// 4690.494 us; speedup vs baseline: 1.3359x; 1.0009x over previous
//
#include <hip/hip_runtime.h>
#include <math.h>

#define BB 256
#define NN 1000
#define DD 128
#define HH 8
#define NP 1024
#define CHROWS 128
#define CLIPV 10.0f
#define SC_QK 0.25f                       // 1/sqrt(16)
#define SC_LG 0.08838834764831845f        // 1/sqrt(128)
#define NEGINF (-INFINITY)
#define LP_FLOOR (-3.0e38f)               // finite stand-in for -inf in output

typedef float  fx4 __attribute__((ext_vector_type(4)));
typedef unsigned short usx4 __attribute__((ext_vector_type(4)));

__device__ __forceinline__ float dot4(float4 a, float4 b) {
    return fmaf(a.x, b.x, fmaf(a.y, b.y, fmaf(a.z, b.z, a.w * b.w)));
}
__device__ __forceinline__ float4 fma4(float p, float4 e, float4 a) {
    a.x = fmaf(p, e.x, a.x); a.y = fmaf(p, e.y, a.y);
    a.z = fmaf(p, e.z, a.z); a.w = fmaf(p, e.w, a.w);
    return a;
}
__device__ __forceinline__ void bf2f(unsigned int u, float& a, float& b) {
    union { unsigned int i; float f; } lo, hi;
    lo.i = u << 16; hi.i = u & 0xffff0000u;
    a = lo.f; b = hi.f;
}
__device__ __forceinline__ unsigned short f2bf_rne(float x) {
    union { float f; unsigned int u; } v; v.f = x;
    unsigned int r = v.u + 0x7FFFu + ((v.u >> 16) & 1u);
    return (unsigned short)(r >> 16);
}
// async global->LDS, 16B per lane; LDS dest is wave-uniform base + lane*16
__device__ __forceinline__ void gl_lds16(const unsigned short* g, unsigned short* l) {
    __builtin_amdgcn_global_load_lds(
        (__attribute__((address_space(1))) void*)(g),
        (__attribute__((address_space(3))) void*)(l), 16, 0, 0);
}

// ---------------- fp32 emb -> bf16 scratch copy, padded to 1024 rows ----------------
__global__ __launch_bounds__(256) void conv_bf16_pad(const float* __restrict__ emb,
                                                     unsigned short* __restrict__ ebf) {
    const int idx = blockIdx.x * 256 + threadIdx.x;     // one 8-bf16 unit (16B out)
    const int b   = idx >> 14;                          // / (1024*16)
    const int row = (idx >> 4) & 1023;
    const int k8  = idx & 15;
    uint4 o = make_uint4(0u, 0u, 0u, 0u);               // pad rows -> zeros
    if (row < NN) {
        const float* p = emb + ((size_t)b * NN + row) * DD + k8 * 8;
        fx4 f0 = __builtin_nontemporal_load((const fx4*)p);
        fx4 f1 = __builtin_nontemporal_load((const fx4*)(p + 4));
        o.x = ((unsigned)f2bf_rne(f0.y) << 16) | f2bf_rne(f0.x);
        o.y = ((unsigned)f2bf_rne(f0.w) << 16) | f2bf_rne(f0.z);
        o.z = ((unsigned)f2bf_rne(f1.y) << 16) | f2bf_rne(f1.x);
        o.w = ((unsigned)f2bf_rne(f1.w) << 16) | f2bf_rne(f1.z);
    }
    *(uint4*)(ebf + (size_t)idx * 8) = o;
}

// ---------------- main decoder ----------------
// The 3 sweeps per step read the SAME 8 chunks (32KB each). Alternating sweep
// direction reuses the 3 chunks still resident in the rotating buffers at
// sweep entry: only 5/8 chunks staged per sweep (chains across sweeps AND
// steps) => 37.5% fetch cut. Buffer map is static: buf = chunk % 3.
//   fwd: resident {0,1,2}; phases 2..6 stage chunk i+1 -> bufs 0,1,2,0,1
//   rev: resident {5,6,7}; phases 2..6 stage chunk 6-i -> bufs 1,0,2,1,0
// Each staged buffer was last read two phases (two barriers) earlier.
// Plain __syncthreads() per phase (drains vmcnt) - validated r2 machinery;
// counted-vmcnt pipelining measured neutral here (r3), so not used.
// NOTE (r8): the fused flash-style single-pass variant failed 3x in the
// harness with no observable error; reverted to this r5-validated artifact.
__global__ __launch_bounds__(1024, 4) void ar_decoder_bf16(
    const float* __restrict__ emb,            // [B][N][D] fp32 (small reads only)
    const unsigned short* __restrict__ embbf, // [B][1024][D] bf16 padded (sweeps)
    const float* __restrict__ Wn,    // [D][3D]  (gk | gv | lk columns)
    const float* __restrict__ Wf,    // [D][D]
    const float* __restrict__ Wc,    // [2D][D]
    const float* __restrict__ Wo,    // [D][D]
    const int*  __restrict__ nsp,    // num_steps
    float* __restrict__ out)         // [B][S][N] log_p then [B][S] actions (as float)
{
    const int b = blockIdx.x;
    const int t = threadIdx.x;
    const int S = nsp[0];
    const float* E  = emb + (size_t)b * (NN * DD);
    const unsigned short* Ebf = embbf + (size_t)b * (1024 * DD);
    const int wv = t >> 6, ln = t & 63;

    __shared__ __align__(16) unsigned short ebuf[3][CHROWS * DD];  // 3 x 32KB staging
    __shared__ __align__(16) float pS[8192];       // scores/p [n][8]; also wsum scratch
    __shared__ __align__(16) float qkT[HH * 132];  // qk [h][132] padded
    __shared__ __align__(16) float wsumL[HH * DD];
    __shared__ __align__(16) float maskF[NP];      // 0 = live, -inf = visited/pad
    __shared__ __align__(16) float zS[NP];         // clipped+masked logits
    __shared__ __align__(16) float ceL[DD], qL[DD], gL[DD], fL[DD], uL[DD];
    __shared__ __align__(16) float fcL[DD], muL[DD], e0L[DD];
    __shared__ __align__(16) float wredM[128], wredS[128];
    __shared__ float mL[HH], lL[HH];
    __shared__ float redA[16], redV[16];
    __shared__ int   redI[16];
    __shared__ float maxvL, logSL;
    __shared__ int   curL, amaxL;

    // stage one 128-row chunk (32KB) of Ebf into ebuf[bi]; all 16 waves, 2KB each
#define STAGE_CHUNK(cidx, bi) do {                                             \
        const unsigned short* _s = Ebf + (size_t)(cidx) * (CHROWS * DD);       \
        unsigned short* _d = &ebuf[bi][0];                                     \
        gl_lds16(_s + wv * 512 + ln * 8,        _d + wv * 512);                \
        gl_lds16(_s + (16 + wv) * 512 + ln * 8, _d + (16 + wv) * 512);         \
    } while (0)
    // stage at phase i the chunk needed at phase i+1 (none resident-side)
#define SWEEP_STAGE(i, f) do {                                                 \
        if ((i) >= 2 && (i) <= 6) {                                            \
            const int _tc = (f) ? (i) + 1 : 6 - (i);                           \
            STAGE_CHUNK(_tc, _tc % 3);                                         \
        }                                                                      \
    } while (0)

    bool fwd = true;

    // pre-stage chunks 0,1,2 for the first (forward) sweep; the prologue's
    // __syncthreads barriers drain vmcnt before first use.
    STAGE_CHUNK(0, 0);
    STAGE_CHUNK(1, 1);
    STAGE_CHUNK(2, 2);

    // ---------------- prologue ----------------
    {   // mean over nodes (8 strips of 125)
        const int d = t & 127, strip = t >> 7;
        float acc = 0.f;
        const int n0 = strip * 125;
        for (int k = 0; k < 125; ++k) acc += E[(n0 + k) * DD + d];
        pS[strip * 128 + d] = acc;
    }
    if (t < DD) e0L[t] = E[t];
    __syncthreads();
    if (t < DD) {
        float ssum = 0.f;
        for (int k = 0; k < 8; ++k) ssum += pS[k * 128 + t];
        muL[t] = ssum * (1.0f / (float)NN);
    }
    __syncthreads();
    if (t < DD) {
        float fc = 0.f;
        for (int i = 0; i < DD; ++i)
            fc += muL[i] * Wf[i * DD + t] + e0L[i] * Wc[i * DD + t];
        fcL[t] = fc;
    }
    maskF[t] = (t == 0 || t >= NN) ? NEGINF : 0.f;
    if (t == 0) curL = 0;
    __syncthreads();

    const size_t out_lp_base = (size_t)b * S * NN;
    const size_t act_base    = (size_t)BB * S * NN + (size_t)b * S;

    for (int s = 0; s < S; ++s) {
        // (0) current node embedding (fp32, exact)
        if (t < DD) ceL[t] = E[curL * DD + t];
        __syncthreads();
        // (1) q = fc + cur_emb @ Wc_bottom  (8-way k-split per output)
        {
            const int d = t >> 3, p = t & 7;
            const int i0 = p * 16;
            float q = 0.f;
            #pragma unroll
            for (int i = 0; i < 16; ++i)
                q += ceL[i0 + i] * Wc[(DD + i0 + i) * DD + d];
            q += __shfl_xor(q, 1);
            q += __shfl_xor(q, 2);
            q += __shfl_xor(q, 4);
            if (p == 0) qL[d] = q + fcL[d];
        }
        __syncthreads();
        // (2) qk[h][d] = 0.25 * sum_k Wk[d][h*16+k] * q[h*16+k]
        {
            const int h = t >> 7, d = t & 127;
            float v = 0.f;
            for (int k = 0; k < 16; ++k)
                v += Wn[d * 384 + h * 16 + k] * qL[h * 16 + k];
            qkT[h * 132 + d] = v * SC_QK;
        }
        __syncthreads();
        // (3) scores sweep (alternating direction, 3-chunk reuse)
        {
            const int dq = t & 3, h = (t >> 2) & 7, o2 = t >> 5;   // o2 in 0..31
            float4 qk4[8];                 // chunks c = dq+4m, elems [c*8, c*8+8)
            #pragma unroll
            for (int m = 0; m < 4; ++m) {
                const float* qp = &qkT[h * 132 + (dq + 4 * m) * 8];
                qk4[2 * m]     = *(const float4*)(qp);
                qk4[2 * m + 1] = *(const float4*)(qp + 4);
            }
            float mloc = NEGINF;
            for (int i = 0; i < 8; ++i) {
                const int ck = fwd ? i : 7 - i;
                SWEEP_STAGE(i, fwd);
                const unsigned short* Eb = &ebuf[ck % 3][0];
                float acc[4];
                #pragma unroll
                for (int j = 0; j < 4; ++j) acc[j] = 0.f;
                #pragma unroll
                for (int j = 0; j < 4; ++j) {
                    const int r = o2 * 4 + j;
                    const uint4* rp = (const uint4*)(Eb + r * DD);
                    #pragma unroll
                    for (int m = 0; m < 4; ++m) {
                        uint4 u = rp[dq + 4 * m];
                        float e0,e1,e2,e3,e4,e5,e6,e7;
                        bf2f(u.x, e0, e1); bf2f(u.y, e2, e3);
                        bf2f(u.z, e4, e5); bf2f(u.w, e6, e7);
                        const float4 qa = qk4[2 * m], qb = qk4[2 * m + 1];
                        acc[j] = fmaf(e0, qa.x, fmaf(e1, qa.y, fmaf(e2, qa.z, fmaf(e3, qa.w, acc[j]))));
                        acc[j] = fmaf(e4, qb.x, fmaf(e5, qb.y, fmaf(e6, qb.z, fmaf(e7, qb.w, acc[j]))));
                    }
                }
                #pragma unroll
                for (int j = 0; j < 4; ++j) {
                    acc[j] += __shfl_xor(acc[j], 1);
                    acc[j] += __shfl_xor(acc[j], 2);
                }
                const int nb = ck * 128 + o2 * 4;
                pS[(nb + dq) * 8 + h] = acc[dq];
                #pragma unroll
                for (int j = 0; j < 4; ++j)
                    mloc = fmaxf(mloc, acc[j] + maskF[nb + j]);   // pad rows -> -inf
                __syncthreads();
            }
            fwd = !fwd;
            // reduce over lanes sharing h (bits 0,1,5)
            mloc = fmaxf(mloc, __shfl_xor(mloc, 1));
            mloc = fmaxf(mloc, __shfl_xor(mloc, 2));
            mloc = fmaxf(mloc, __shfl_xor(mloc, 32));
            if ((t & 35) == 0) wredM[wv * 8 + h] = mloc;
        }
        __syncthreads();
        if (t < HH) {
            float m = wredM[t];
            for (int w = 1; w < 16; ++w) m = fmaxf(m, wredM[w * 8 + t]);
            mL[t] = m;
        }
        __syncthreads();
        // (4) p = exp(s + mask - m) in place + fused per-h partial sums
        {
            float4* pS4 = (float4*)pS;
            float4 a = pS4[t * 2], c = pS4[t * 2 + 1];
            const float mf = maskF[t];
            a.x = expf(a.x + mf - mL[0]); a.y = expf(a.y + mf - mL[1]);
            a.z = expf(a.z + mf - mL[2]); a.w = expf(a.w + mf - mL[3]);
            c.x = expf(c.x + mf - mL[4]); c.y = expf(c.y + mf - mL[5]);
            c.z = expf(c.z + mf - mL[6]); c.w = expf(c.w + mf - mL[7]);
            pS4[t * 2] = a; pS4[t * 2 + 1] = c;
            #pragma unroll
            for (int off = 1; off < 64; off <<= 1) {
                a.x += __shfl_xor(a.x, off); a.y += __shfl_xor(a.y, off);
                a.z += __shfl_xor(a.z, off); a.w += __shfl_xor(a.w, off);
                c.x += __shfl_xor(c.x, off); c.y += __shfl_xor(c.y, off);
                c.z += __shfl_xor(c.z, off); c.w += __shfl_xor(c.w, off);
            }
            if (ln == 0) {
                ((float4*)wredS)[wv * 2] = a;
                ((float4*)wredS)[wv * 2 + 1] = c;
            }
        }
        __syncthreads();
        if (t < HH) {
            float ssum = 0.f;
            for (int w = 0; w < 16; ++w) ssum += wredS[w * 8 + t];
            lL[t] = ssum;
        }
        // (5) wsum sweep (alternating direction, 3-chunk reuse)
        {
            const int d8 = t & 15, g2 = (t >> 4) & 3, gh = wv & 7, hp = t >> 9;
            float acc[4][8];
            #pragma unroll
            for (int hh = 0; hh < 4; ++hh)
                #pragma unroll
                for (int i = 0; i < 8; ++i) acc[hh][i] = 0.f;
            const float4* pS4 = (const float4*)pS;
            for (int i = 0; i < 8; ++i) {
                const int ck = fwd ? i : 7 - i;
                SWEEP_STAGE(i, fwd);
                const unsigned short* Eb = &ebuf[ck % 3][0];
                #pragma unroll
                for (int k2 = 0; k2 < 4; ++k2) {
                    const int r = k2 * 32 + gh * 4 + g2;
                    const int n = ck * 128 + r;
                    uint4 u = *(const uint4*)(Eb + r * DD + d8 * 8);
                    float e[8];
                    bf2f(u.x, e[0], e[1]); bf2f(u.y, e[2], e[3]);
                    bf2f(u.z, e[4], e[5]); bf2f(u.w, e[6], e[7]);
                    const float4 p4 = pS4[n * 2 + hp];
                    #pragma unroll
                    for (int i2 = 0; i2 < 8; ++i2) {
                        acc[0][i2] = fmaf(p4.x, e[i2], acc[0][i2]);
                        acc[1][i2] = fmaf(p4.y, e[i2], acc[1][i2]);
                        acc[2][i2] = fmaf(p4.z, e[i2], acc[2][i2]);
                        acc[3][i2] = fmaf(p4.w, e[i2], acc[3][i2]);
                    }
                }
                __syncthreads();
            }
            fwd = !fwd;
            // reduce over g2 (lane bits 4,5)
            #pragma unroll
            for (int hh = 0; hh < 4; ++hh)
                #pragma unroll
                for (int i = 0; i < 8; ++i) {
                    acc[hh][i] += __shfl_xor(acc[hh][i], 16);
                    acc[hh][i] += __shfl_xor(acc[hh][i], 32);
                }
            if (ln < 16) {   // ln == d8, g2 == 0
                #pragma unroll
                for (int hh = 0; hh < 4; ++hh) {
                    float4* dst = (float4*)&pS[gh * 1024 + (hp * 4 + hh) * 128 + d8 * 8];
                    dst[0] = make_float4(acc[hh][0], acc[hh][1], acc[hh][2], acc[hh][3]);
                    dst[1] = make_float4(acc[hh][4], acc[hh][5], acc[hh][6], acc[hh][7]);
                }
            }
            __syncthreads();
            {
                const int h = t >> 7, d = t & 127;
                float ssum = 0.f;
                #pragma unroll
                for (int g = 0; g < 8; ++g) ssum += pS[g * 1024 + h * 128 + d];
                wsumL[h * DD + d] = ssum;
            }
            __syncthreads();
        }
        // (6) g[c] = (wsum[h]·Wv[:,c]) / l[h]   (8-way d-split)
        {
            const int c = t >> 3, p = t & 7, h = c >> 4;
            const int d0 = p * 16;
            float g = 0.f;
            #pragma unroll
            for (int i = 0; i < 16; ++i)
                g += wsumL[h * DD + d0 + i] * Wn[(d0 + i) * 384 + DD + c];
            g += __shfl_xor(g, 1);
            g += __shfl_xor(g, 2);
            g += __shfl_xor(g, 4);
            if (p == 0) gL[c] = g / lL[h];
        }
        __syncthreads();
        // (7) f = g @ W_out   (8-way i-split)
        {
            const int d = t >> 3, p = t & 7;
            const int i0 = p * 16;
            float f = 0.f;
            #pragma unroll
            for (int i = 0; i < 16; ++i)
                f += gL[i0 + i] * Wo[(i0 + i) * DD + d];
            f += __shfl_xor(f, 1);
            f += __shfl_xor(f, 2);
            f += __shfl_xor(f, 4);
            if (p == 0) fL[d] = f;
        }
        __syncthreads();
        // (8) u[d] = sc * sum_k Wl[d][k] * f[k]   (8-way k-split)
        {
            const int d = t >> 3, p = t & 7;
            const int k0 = p * 16;
            float u = 0.f;
            #pragma unroll
            for (int k = 0; k < 16; ++k)
                u += Wn[d * 384 + 256 + k0 + k] * fL[k0 + k];
            u += __shfl_xor(u, 1);
            u += __shfl_xor(u, 2);
            u += __shfl_xor(u, 4);
            if (p == 0) uL[d] = u * SC_LG;
        }
        __syncthreads();
        // (9) logits sweep (alternating direction, 3-chunk reuse) -> zS
        {
            const int q8 = t & 7, rr = t >> 3;   // rr in 0..127 per chunk
            const float4* uL4 = (const float4*)uL;
            const float4 ua0 = uL4[q8 * 2],       ub0 = uL4[q8 * 2 + 1];
            const float4 ua1 = uL4[(q8 + 8) * 2], ub1 = uL4[(q8 + 8) * 2 + 1];
            for (int i = 0; i < 8; ++i) {
                const int ck = fwd ? i : 7 - i;
                SWEEP_STAGE(i, fwd);
                const unsigned short* Eb = &ebuf[ck % 3][0];
                const int n = ck * 128 + rr;
                uint4 u0 = *(const uint4*)(Eb + rr * DD + q8 * 8);
                uint4 u1 = *(const uint4*)(Eb + rr * DD + (q8 + 8) * 8);
                float e0,e1,e2,e3,e4,e5,e6,e7;
                bf2f(u0.x, e0, e1); bf2f(u0.y, e2, e3);
                bf2f(u0.z, e4, e5); bf2f(u0.w, e6, e7);
                float lg;
                lg = fmaf(e0, ua0.x, fmaf(e1, ua0.y, fmaf(e2, ua0.z, e3 * ua0.w)));
                lg = fmaf(e4, ub0.x, fmaf(e5, ub0.y, fmaf(e6, ub0.z, fmaf(e7, ub0.w, lg))));
                bf2f(u1.x, e0, e1); bf2f(u1.y, e2, e3);
                bf2f(u1.z, e4, e5); bf2f(u1.w, e6, e7);
                lg = fmaf(e0, ua1.x, fmaf(e1, ua1.y, fmaf(e2, ua1.z, fmaf(e3, ua1.w, lg))));
                lg = fmaf(e4, ub1.x, fmaf(e5, ub1.y, fmaf(e6, ub1.z, fmaf(e7, ub1.w, lg))));
                lg += __shfl_xor(lg, 1);
                lg += __shfl_xor(lg, 2);
                lg += __shfl_xor(lg, 4);
                if (q8 == 0)
                    zS[n] = (n < NN) ? (CLIPV * tanhf(lg) + maskF[n]) : NEGINF;
                __syncthreads();
            }
            fwd = !fwd;
        }
        // (10) log-softmax + argmax from zS, output, state update
        {
            const float z = zS[t];
            float v = z; int idx = t;
            #pragma unroll
            for (int off = 1; off < 64; off <<= 1) {
                float v2 = __shfl_xor(v, off);
                int   i2 = __shfl_xor(idx, off);
                if (v2 > v || (v2 == v && i2 < idx)) { v = v2; idx = i2; }
            }
            if (ln == 0) { redV[wv] = v; redI[wv] = idx; }
            __syncthreads();
            if (t == 0) {
                float bv = redV[0]; int bi = redI[0];
                for (int ww = 1; ww < 16; ++ww)
                    if (redV[ww] > bv || (redV[ww] == bv && redI[ww] < bi)) { bv = redV[ww]; bi = redI[ww]; }
                maxvL = bv; amaxL = bi;
            }
            __syncthreads();
            float e = expf(z - maxvL);
            #pragma unroll
            for (int off = 1; off < 64; off <<= 1) e += __shfl_xor(e, off);
            if (ln == 0) redA[wv] = e;
            __syncthreads();
            if (t == 0) {
                float ssum = 0.f;
                for (int ww = 0; ww < 16; ++ww) ssum += redA[ww];
                logSL = logf(ssum);
            }
            __syncthreads();
            if (t < NN) {
                float lp = fmaxf(z - maxvL - logSL, LP_FLOOR);
                __builtin_nontemporal_store(lp, &out[out_lp_base + (size_t)s * NN + t]);
            }
            if (t == 0) {
                __builtin_nontemporal_store((float)amaxL, &out[act_base + s]);
                maskF[amaxL] = NEGINF;
                curL = amaxL;
            }
        }
        __syncthreads();
    }
#undef SWEEP_STAGE
#undef STAGE_CHUNK
}

// ---------------- fp32 fallback (round-2 kernel, validated) ----------------
__global__ __launch_bounds__(1024) void ar_decoder_f32(
    const float* __restrict__ emb, const float* __restrict__ Wn,
    const float* __restrict__ Wf, const float* __restrict__ Wc,
    const float* __restrict__ Wo, const int* __restrict__ nsp,
    float* __restrict__ out)
{
    const int b = blockIdx.x;
    const int t = threadIdx.x;
    const int S = nsp[0];
    const float*  E  = emb + (size_t)b * (NN * DD);
    const float4* E4 = (const float4*)E;

    __shared__ __align__(16) float pS[8192];
    __shared__ __align__(16) float qkT[1024];
    __shared__ __align__(16) float wsumL[HH * DD];
    __shared__ __align__(16) float maskF[NP];
    __shared__ __align__(16) float ceL[DD], qL[DD], gL[DD], fL[DD], uL[DD], fcL[DD], muL[DD], e0L[DD];
    __shared__ float mL[HH], lL[HH];
    __shared__ float redA[16], redV[16];
    __shared__ int   redI[16];
    __shared__ float maxvL, logSL;
    __shared__ int   curL, amaxL;

    {
        const int d = t & 127, strip = t >> 7;
        float acc = 0.f;
        const int n0 = strip * 125;
        for (int k = 0; k < 125; ++k) acc += E[(n0 + k) * DD + d];
        pS[strip * 128 + d] = acc;
    }
    if (t < DD) e0L[t] = E[t];
    __syncthreads();
    if (t < DD) {
        float ssum = 0.f;
        for (int k = 0; k < 8; ++k) ssum += pS[k * 128 + t];
        muL[t] = ssum * (1.0f / (float)NN);
    }
    __syncthreads();
    if (t < DD) {
        float fc = 0.f;
        for (int i = 0; i < DD; ++i)
            fc += muL[i] * Wf[i * DD + t] + e0L[i] * Wc[i * DD + t];
        fcL[t] = fc;
    }
    maskF[t] = (t == 0 || t >= NN) ? NEGINF : 0.f;
    if (t == 0) curL = 0;
    __syncthreads();

    const size_t out_lp_base = (size_t)b * S * NN;
    const size_t act_base    = (size_t)BB * S * NN + (size_t)b * S;

    for (int s = 0; s < S; ++s) {
        if (t < DD) ceL[t] = E[curL * DD + t];
        __syncthreads();
        if (t < DD) {
            float q = fcL[t];
            for (int i = 0; i < DD; ++i) q += ceL[i] * Wc[(DD + i) * DD + t];
            qL[t] = q;
        }
        __syncthreads();
        {
            const int h = t >> 7, d = t & 127;
            float v = 0.f;
            for (int k = 0; k < 16; ++k) v += Wn[d * 384 + h * 16 + k] * qL[h * 16 + k];
            qkT[(d >> 2) * 32 + h * 4 + (d & 3)] = v * SC_QK;
        }
        __syncthreads();
        {
            const int dq = t & 3, h = (t >> 2) & 7, o = t >> 5;
            float4 qk4[8];
            const float4* qkT4 = (const float4*)qkT;
            #pragma unroll
            for (int i = 0; i < 8; ++i) qk4[i] = qkT4[(i * 4 + dq) * 8 + h];
            for (int oi = 0; oi < 4; ++oi) {
                const int oe = oi * 32 + o;
                float acc[8] = {0,0,0,0,0,0,0,0};
                #pragma unroll
                for (int i = 0; i < 8; ++i) {
                    const int d4 = i * 4 + dq;
                    #pragma unroll
                    for (int j = 0; j < 8; ++j) {
                        int row = oe * 8 + j; if (row > NN - 1) row = NN - 1;
                        acc[j] += dot4(E4[row * 32 + d4], qk4[i]);
                    }
                }
                #pragma unroll
                for (int j = 0; j < 8; ++j) {
                    acc[j] += __shfl_xor(acc[j], 1);
                    acc[j] += __shfl_xor(acc[j], 2);
                }
                const int j0 = 2 * dq;
                pS[(oe * 8 + j0)     * 8 + h] = acc[j0];
                pS[(oe * 8 + j0 + 1) * 8 + h] = acc[j0 + 1];
            }
        }
        __syncthreads();
        {
            const int w = t >> 6, lane = t & 63;
            const int h = w & 7, half = (w >> 3) * 512;
            float m = NEGINF;
            for (int k = 0; k < 8; ++k) {
                const int n = half + k * 64 + lane;
                m = fmaxf(m, pS[n * 8 + h] + maskF[n]);
            }
            for (int off = 32; off > 0; off >>= 1) m = fmaxf(m, __shfl_xor(m, off));
            if (lane == 0) redA[w] = m;
        }
        __syncthreads();
        if (t < HH) mL[t] = fmaxf(redA[t], redA[8 + t]);
        __syncthreads();
        {
            float4* pS4 = (float4*)pS;
            float4 a = pS4[t * 2], c = pS4[t * 2 + 1];
            const float mf = maskF[t];
            a.x = expf(a.x + mf - mL[0]); a.y = expf(a.y + mf - mL[1]);
            a.z = expf(a.z + mf - mL[2]); a.w = expf(a.w + mf - mL[3]);
            c.x = expf(c.x + mf - mL[4]); c.y = expf(c.y + mf - mL[5]);
            c.z = expf(c.z + mf - mL[6]); c.w = expf(c.w + mf - mL[7]);
            pS4[t * 2] = a; pS4[t * 2 + 1] = c;
        }
        __syncthreads();
        {
            const int w = t >> 6, lane = t & 63;
            const int h = w & 7, half = (w >> 3) * 512;
            float sum = 0.f;
            for (int k = 0; k < 8; ++k) sum += pS[(half + k * 64 + lane) * 8 + h];
            for (int off = 32; off > 0; off >>= 1) sum += __shfl_xor(sum, off);
            if (lane == 0) redA[w] = sum;
        }
        __syncthreads();
        if (t < HH) lL[t] = redA[t] + redA[8 + t];
        __syncthreads();
        {
            float4 acc[8];
            const int d4 = t & 31, nq = t >> 5;
            #pragma unroll
            for (int h = 0; h < 8; ++h) acc[h] = make_float4(0, 0, 0, 0);
            const float4* pS4 = (const float4*)pS;
            for (int k = 0; k < 32; ++k) {
                const int n = nq * 32 + k;
                const int row = (n > NN - 1) ? NN - 1 : n;
                float4 e4 = E4[row * 32 + d4];
                float4 pa = pS4[n * 2], pb = pS4[n * 2 + 1];
                acc[0] = fma4(pa.x, e4, acc[0]); acc[1] = fma4(pa.y, e4, acc[1]);
                acc[2] = fma4(pa.z, e4, acc[2]); acc[3] = fma4(pa.w, e4, acc[3]);
                acc[4] = fma4(pb.x, e4, acc[4]); acc[5] = fma4(pb.y, e4, acc[5]);
                acc[6] = fma4(pb.z, e4, acc[6]); acc[7] = fma4(pb.w, e4, acc[7]);
            }
            __syncthreads();
            #pragma unroll
            for (int h = 0; h < 8; ++h) {
                acc[h].x += __shfl_xor(acc[h].x, 32);
                acc[h].y += __shfl_xor(acc[h].y, 32);
                acc[h].z += __shfl_xor(acc[h].z, 32);
                acc[h].w += __shfl_xor(acc[h].w, 32);
            }
            const int w = t >> 6, lane = t & 63;
            float4* red4 = (float4*)pS;
            for (int rh = 0; rh < 2; ++rh) {
                if (lane < 32) {
                    #pragma unroll
                    for (int hh = 0; hh < 4; ++hh)
                        red4[(w * 4 + hh) * 32 + d4] = acc[rh * 4 + hh];
                }
                __syncthreads();
                if (t < 512) {
                    const int hh = t >> 7, d = t & 127;
                    float ssum = 0.f;
                    for (int ww = 0; ww < 16; ++ww) ssum += pS[(ww * 4 + hh) * 128 + d];
                    wsumL[(rh * 4 + hh) * DD + d] = ssum;
                }
                __syncthreads();
            }
        }
        if (t < DD) {
            const int h = t >> 4;
            float g = 0.f;
            for (int d = 0; d < DD; ++d) g += wsumL[h * DD + d] * Wn[d * 384 + DD + t];
            gL[t] = g / lL[h];
        }
        __syncthreads();
        if (t < DD) {
            float f = 0.f;
            for (int i = 0; i < DD; ++i) f += gL[i] * Wo[i * DD + t];
            fL[t] = f;
        }
        __syncthreads();
        if (t < DD) {
            float u = 0.f;
            for (int k = 0; k < DD; ++k) u += Wn[t * 384 + 256 + k] * fL[k];
            uL[t] = u * SC_LG;
        }
        __syncthreads();
        {
            const int row = (t > NN - 1) ? NN - 1 : t;
            float lg = 0.f;
            const float4* uL4 = (const float4*)uL;
            for (int d4 = 0; d4 < 32; ++d4) lg += dot4(E4[row * 32 + d4], uL4[d4]);
            const float z = CLIPV * tanhf(lg) + maskF[t];
            float v = z; int idx = t;
            for (int off = 1; off < 64; off <<= 1) {
                float v2 = __shfl_xor(v, off);
                int   i2 = __shfl_xor(idx, off);
                if (v2 > v || (v2 == v && i2 < idx)) { v = v2; idx = i2; }
            }
            const int w = t >> 6, lane = t & 63;
            if (lane == 0) { redV[w] = v; redI[w] = idx; }
            __syncthreads();
            if (t == 0) {
                float bv = redV[0]; int bi = redI[0];
                for (int ww = 1; ww < 16; ++ww)
                    if (redV[ww] > bv || (redV[ww] == bv && redI[ww] < bi)) { bv = redV[ww]; bi = redI[ww]; }
                maxvL = bv; amaxL = bi;
            }
            __syncthreads();
            float e = expf(z - maxvL);
            for (int off = 1; off < 64; off <<= 1) e += __shfl_xor(e, off);
            if (lane == 0) redA[w] = e;
            __syncthreads();
            if (t == 0) {
                float ssum = 0.f;
                for (int ww = 0; ww < 16; ++ww) ssum += redA[ww];
                logSL = logf(ssum);
            }
            __syncthreads();
            if (t < NN) {
                float lp = z - maxvL - logSL;
                out[out_lp_base + (size_t)s * NN + t] = fmaxf(lp, LP_FLOOR);
            }
            if (t == 0) {
                out[act_base + s] = (float)amaxL;
                maskF[amaxL] = NEGINF;
                curL = amaxL;
            }
        }
        __syncthreads();
    }
}

extern "C" void kernel_launch(void* const* d_in, const int* in_sizes, int n_in,
                              void* d_out, int out_size, void* d_ws, size_t ws_size,
                              hipStream_t stream) {
    const float* emb = (const float*)d_in[0];
    const float* Wn  = (const float*)d_in[1];
    const float* Wf  = (const float*)d_in[2];
    const float* Wc  = (const float*)d_in[3];
    const float* Wo  = (const float*)d_in[4];
    const int*   nsp = (const int*)d_in[5];
    const size_t need = (size_t)BB * 1024 * DD * sizeof(unsigned short);  // 67.1 MB padded
    if (ws_size >= need) {
        unsigned short* ebf = (unsigned short*)d_ws;
        const int nunits = BB * 1024 * 16;              // 8-bf16 units
        conv_bf16_pad<<<dim3(nunits / 256), dim3(256), 0, stream>>>(emb, ebf);
        ar_decoder_bf16<<<dim3(BB), dim3(1024), 0, stream>>>(emb, ebf, Wn, Wf, Wc, Wo, nsp, (float*)d_out);
    } else {
        ar_decoder_f32<<<dim3(BB), dim3(1024), 0, stream>>>(emb, Wn, Wf, Wc, Wo, nsp, (float*)d_out);
    }
}